// Round 8
// baseline (239.503 us; speedup 1.0000x reference)
//
#include <hip/hip_runtime.h>
#include <math.h>

typedef float f32x16 __attribute__((ext_vector_type(16)));
typedef short s16x8 __attribute__((ext_vector_type(8)));
typedef unsigned int u32;

namespace {
constexpr int B_ = 4, H_ = 16, T_ = 2048, K_ = 128, V_ = 128;
constexpr int BHn = B_ * H_;
constexpr int C = 32;            // chunk length
constexpr int NCH = T_ / C;      // 64 chunks
constexpr int NS = 4;            // V slices (seq pass)
constexpr int VS = V_ / NS;      // 32 cols per block
constexpr float SCALE = 0.08838834764831845f; // 128^-0.5
constexpr int SK = 136;          // ushort stride, [*][128] arrays (16B-aligned rows)
constexpr int SRT = 36;          // ushort stride, KhT [128][32]: 72B rows -> 2-way-free scatter
constexpr int SRU = 36;          // ushort stride, UT/Bb [32][32]
constexpr int SG = 48;           // ushort stride, Tl/Gl tiles [32][32] (96B, 16B-aligned)
constexpr int SF = 36;           // f32 stride, pre-pass Mm
constexpr size_t WSCH = 4608;    // ws bytes per (head,chunk): T 2048 | G 2048 | scal 384 | pad
}

__device__ __forceinline__ ushort f2bf(float x) {
  unsigned u = __builtin_bit_cast(unsigned, x);
  u += 0x7FFF + ((u >> 16) & 1);       // RNE
  return (ushort)(u >> 16);
}
__device__ __forceinline__ int rowmap(int i, int lh) { return (i & 3) + 8 * (i >> 2) + 4 * lh; }

// barrier waiting only on LDS ops: global loads/stores stay in flight
__device__ __forceinline__ void bar_lds() {
  asm volatile("s_waitcnt lgkmcnt(0)" ::: "memory");
  __builtin_amdgcn_s_barrier();
  asm volatile("" ::: "memory");
}

// 16B fragment from an 8B-aligned (not 16B) LDS row: two b64 loads
__device__ __forceinline__ s16x8 ld8u(const ushort* p) {
  uint2 a = *(const uint2*)(p);
  uint2 b = *(const uint2*)(p + 4);
  int4 r = make_int4((int)a.x, (int)a.y, (int)b.x, (int)b.y);
  return __builtin_bit_cast(s16x8, r);
}

// full-K (128) tile matmul: A * Barr^T, both stride SK
__device__ __forceinline__ f32x16 mm8(const ushort* A, const ushort* B, int lr, int lh) {
  f32x16 a0, a1;
  #pragma unroll
  for (int i = 0; i < 16; ++i) { a0[i] = 0.f; a1[i] = 0.f; }
  #pragma unroll
  for (int kb = 0; kb < 8; kb += 2) {
    const int o0 = lr * SK + 16 * kb + 8 * lh, o1 = o0 + 16;
    a0 = __builtin_amdgcn_mfma_f32_32x32x16_bf16(*(const s16x8*)(A + o0),
                                                 *(const s16x8*)(B + o0), a0, 0, 0, 0);
    a1 = __builtin_amdgcn_mfma_f32_32x32x16_bf16(*(const s16x8*)(A + o1),
                                                 *(const s16x8*)(B + o1), a1, 0, 0, 0);
  }
  return a0 + a1;
}

// ============ pass 1: chunk-local precompute (4096 independent blocks) ============
__global__ __launch_bounds__(256, 2)
void gdn_pre_kernel(const float* __restrict__ qg, const float* __restrict__ kg,
                    const float* __restrict__ gg, const float* __restrict__ bg,
                    char* __restrict__ ws)
{
  const int bid = blockIdx.x;
  const int bh = bid >> 6, ch = bid & 63;
  const int t = threadIdx.x, w = t >> 6, l = t & 63, lr = l & 31, lh = l >> 5;
  const int r8 = t >> 3, c8 = t & 7;
  const int t0 = ch * C;

  __shared__ __align__(16) ushort Kh[C * SK], Qh[C * SK];
  __shared__ __align__(16) float Mm[C * SF];
  __shared__ __align__(16) ushort Tt[C * 32], Gt[C * 32];
  __shared__ float ls_g[C], ls_b[C], ls_eb[C], ls_emb[C];

  { // stage + normalize q,k
    const float4* q4 = (const float4*)(qg + ((size_t)bh * T_ + t0 + r8) * K_);
    const float4* k4 = (const float4*)(kg + ((size_t)bh * T_ + t0 + r8) * K_);
    float4 qv[4], kv[4]; float sq = 0.f, sk = 0.f;
    #pragma unroll
    for (int c = 0; c < 4; ++c) {
      qv[c] = q4[c8 + 8 * c]; kv[c] = k4[c8 + 8 * c];
      sq += qv[c].x*qv[c].x + qv[c].y*qv[c].y + qv[c].z*qv[c].z + qv[c].w*qv[c].w;
      sk += kv[c].x*kv[c].x + kv[c].y*kv[c].y + kv[c].z*kv[c].z + kv[c].w*kv[c].w;
    }
    sq += __shfl_xor(sq, 1); sq += __shfl_xor(sq, 2); sq += __shfl_xor(sq, 4);
    sk += __shfl_xor(sk, 1); sk += __shfl_xor(sk, 2); sk += __shfl_xor(sk, 4);
    const float niq = SCALE / fmaxf(sqrtf(sq), 1e-12f);
    const float nik = 1.0f / fmaxf(sqrtf(sk), 1e-12f);
    #pragma unroll
    for (int c = 0; c < 4; ++c) {
      const int f4 = c8 + 8 * c;
      uint2 upk, upq;
      upk.x = (u32)f2bf(kv[c].x*nik) | ((u32)f2bf(kv[c].y*nik) << 16);
      upk.y = (u32)f2bf(kv[c].z*nik) | ((u32)f2bf(kv[c].w*nik) << 16);
      upq.x = (u32)f2bf(qv[c].x*niq) | ((u32)f2bf(qv[c].y*niq) << 16);
      upq.y = (u32)f2bf(qv[c].z*niq) | ((u32)f2bf(qv[c].w*niq) << 16);
      *(uint2*)(Kh + r8 * SK + f4 * 4) = upk;
      *(uint2*)(Qh + r8 * SK + f4 * 4) = upq;
    }
    if (t < C)          ls_g[t]     = gg[(size_t)bh * T_ + t0 + t];
    else if (t < 2 * C) ls_b[t - C] = bg[(size_t)bh * T_ + t0 + t - C];
  }
  __syncthreads();
  if (w == 3 && l < 32) {   // inclusive prefix of g
    float x = ls_g[l];
    #pragma unroll
    for (int d = 1; d < 32; d <<= 1) { float y = __shfl_up(x, d); if (l >= d) x += y; }
    ls_eb[l] = expf(x); ls_emb[l] = expf(-x);
  }
  if (w == 0) {
    f32x16 acc = mm8(Kh, Kh, lr, lh);
    #pragma unroll
    for (int i = 0; i < 16; ++i) Mm[rowmap(i, lh) * SF + lr] = acc[i];
  }
  if (w == 1) {
    f32x16 acc = mm8(Qh, Kh, lr, lh);
    #pragma unroll
    for (int i = 0; i < 16; ++i) {
      int row = rowmap(i, lh);
      Gt[row * 32 + lr] = (lr <= row) ? f2bf(acc[i]) : (ushort)0;
    }
  }
  __syncthreads();
  if (w == 2 && l < 32) {   // T = (I + tril_strict(diag(b) M))^-1, column l
    const int j = l;
    float x[32];
    #pragma unroll
    for (int m = 0; m < 32; ++m) x[m] = (m == j) ? 1.f : 0.f;
    #pragma unroll
    for (int r = 1; r < 32; ++r) {
      const float* mr = Mm + r * SF;
      float p0 = 0.f, p1 = 0.f, p2 = 0.f, p3 = 0.f;
      #pragma unroll
      for (int jb = 0; jb + 4 <= r; jb += 4) {
        float4 m4 = *(const float4*)(mr + jb);
        p0 = fmaf(m4.x, x[jb + 0], p0);
        p1 = fmaf(m4.y, x[jb + 1], p1);
        p2 = fmaf(m4.z, x[jb + 2], p2);
        p3 = fmaf(m4.w, x[jb + 3], p3);
      }
      #pragma unroll
      for (int m = (r & ~3); m < r; ++m) p1 = fmaf(mr[m], x[m], p1);
      float xr = -ls_b[r] * ((p0 + p1) + (p2 + p3));
      if (r > j) x[r] = xr;
    }
    #pragma unroll
    for (int r = 0; r < 32; ++r) Tt[r * 32 + j] = f2bf(x[r]);
  }
  __syncthreads();
  { // copy to ws  (scal: eb[32] | interleaved (bev,bet)[32] pairs)
    char* wsb = ws + ((size_t)bh * NCH + ch) * WSCH;
    u32* wT = (u32*)wsb; u32* wG = (u32*)(wsb + 2048); float* wS = (float*)(wsb + 4096);
    const u32* sT = (const u32*)Tt; const u32* sG = (const u32*)Gt;
    wT[t] = sT[t]; wT[t + 256] = sT[t + 256];
    wG[t] = sG[t]; wG[t + 256] = sG[t + 256];
    if (t < 32)      wS[t] = ls_eb[t];
    else if (t < 96) {
      int j = t - 32, r = j >> 1;
      wS[t] = (j & 1) ? ls_b[r] : ls_b[r] * ls_emb[r];
    }
  }
}

// ============ pass 2: sequential scan over chunks (256 blocks) ============
__global__ __launch_bounds__(256, 1)
void gdn_seq_kernel(const float* __restrict__ qg, const float* __restrict__ kg,
                    const float* __restrict__ vg, const float* __restrict__ s0,
                    const char* __restrict__ ws, float* __restrict__ out)
{
  const int bid = blockIdx.x;
  // co-locate the 4 V-slices of a head on one XCD (shared q/k/ws L2 reuse)
  const int xcd = bid & 7, qd = bid >> 3;
  const int bh = (qd >> 2) * 8 + xcd;
  const int v0 = (qd & 3) * VS;
  const int t = threadIdx.x, w = t >> 6, l = t & 63, lr = l & 31, lh = l >> 5;
  const int ts = t & 127;               // stager index (valid for w>=2)
  const int r4 = ts >> 2, c4 = ts & 3;  // stager: row 0..31, quarter-lane 0..3

  __shared__ __align__(16) ushort Kh[2][C * SK], Qh[2][C * SK];
  __shared__ __align__(16) ushort KhT[2][K_ * SRT];
  __shared__ __align__(16) ushort Tl[2][C * SG], Gl[3][C * SG];
  __shared__ __align__(16) float  vl[2][C * VS];
  __shared__ __align__(16) float  ls_eb[3][C];
  __shared__ __align__(16) float  ls_bbf[2][2 * C];   // interleaved (bev,bet)
  __shared__ __align__(16) ushort UT[2][32 * SRU], Bb[32 * SRU];
  __shared__ __align__(16) ushort SbT[32 * SK];       // bf16 S^T [v][k]

  // register-resident state: wave w owns k-rows [32w,32w+32), col v0+lr
  f32x16 S;
  {
    const float* sp = s0 + ((size_t)bh * K_ + 32 * w) * V_ + v0 + lr;
    #pragma unroll
    for (int i = 0; i < 16; i += 2) {
      int row = rowmap(i, lh);
      S[i]     = sp[(size_t)row * V_];
      S[i + 1] = sp[(size_t)(row + 1) * V_];
      *(u32*)(SbT + lr * SK + 32 * w + row) =
          (u32)f2bf(S[i]) | ((u32)f2bf(S[i + 1]) << 16);
    }
  }

  const float* qh = qg + (size_t)bh * T_ * K_;
  const float* kh = kg + (size_t)bh * T_ * K_;
  const float* vh = vg + (size_t)bh * T_ * V_;
  const char* wsh = ws + (size_t)bh * NCH * WSCH;
  float* oh = out + (size_t)bh * T_ * V_;

  // stager prefetch registers (w2/w3 only): full 128-elem rows, 8 float4 each
  float4 pq[8], pk[8], pv[2];
  u32 pT[4], pG[4]; float psc = 0.f;

  auto prefetch = [&](int cc) {
    const float4* q4 = (const float4*)(qh + (size_t)(cc * C + r4) * K_);
    const float4* k4 = (const float4*)(kh + (size_t)(cc * C + r4) * K_);
    #pragma unroll
    for (int j = 0; j < 8; ++j) { pq[j] = q4[c4 + 4 * j]; pk[j] = k4[c4 + 4 * j]; }
    const float4* v4 = (const float4*)(vh + (size_t)(cc * C + r4) * V_ + v0);
    pv[0] = v4[c4]; pv[1] = v4[c4 + 4];
    const char* wsb = wsh + (size_t)cc * WSCH;
    #pragma unroll
    for (int j = 0; j < 4; ++j) {
      pT[j] = ((const u32*)wsb)[ts + 128 * j];
      pG[j] = ((const u32*)(wsb + 2048))[ts + 128 * j];
    }
    psc = (ts < 96) ? ((const float*)(wsb + 4096))[ts] : 0.f;
  };
  auto stage = [&](int b, int b3) {
    float sq = 0.f, sk = 0.f;
    #pragma unroll
    for (int j = 0; j < 8; ++j) {
      sq += pq[j].x*pq[j].x + pq[j].y*pq[j].y + pq[j].z*pq[j].z + pq[j].w*pq[j].w;
      sk += pk[j].x*pk[j].x + pk[j].y*pk[j].y + pk[j].z*pk[j].z + pk[j].w*pk[j].w;
    }
    sq += __shfl_xor(sq, 1); sq += __shfl_xor(sq, 2);
    sk += __shfl_xor(sk, 1); sk += __shfl_xor(sk, 2);
    const float niq = SCALE / fmaxf(sqrtf(sq), 1e-12f);
    const float nik = 1.0f / fmaxf(sqrtf(sk), 1e-12f);
    #pragma unroll
    for (int j = 0; j < 8; ++j) {
      const int f4 = c4 + 4 * j;
      ushort k0 = f2bf(pk[j].x * nik), k1 = f2bf(pk[j].y * nik);
      ushort k2 = f2bf(pk[j].z * nik), k3 = f2bf(pk[j].w * nik);
      uint2 upk, upq;
      upk.x = (u32)k0 | ((u32)k1 << 16);
      upk.y = (u32)k2 | ((u32)k3 << 16);
      upq.x = (u32)f2bf(pq[j].x * niq) | ((u32)f2bf(pq[j].y * niq) << 16);
      upq.y = (u32)f2bf(pq[j].z * niq) | ((u32)f2bf(pq[j].w * niq) << 16);
      *(uint2*)(&Kh[b][0] + r4 * SK + 4 * f4) = upk;
      *(uint2*)(&Qh[b][0] + r4 * SK + 4 * f4) = upq;
      ushort* kt = &KhT[b][0] + (4 * f4) * SRT + r4;
      kt[0] = k0; kt[SRT] = k1; kt[2 * SRT] = k2; kt[3 * SRT] = k3;
    }
    *(float4*)(&vl[b][0] + r4 * VS + 4 * c4) = pv[0];
    *(float4*)(&vl[b][0] + r4 * VS + 4 * (c4 + 4)) = pv[1];
    #pragma unroll
    for (int j = 0; j < 4; ++j) {
      int e = ts + 128 * j;
      *(u32*)(&Tl[b][0]  + (e >> 4) * SG + 2 * (e & 15)) = pT[j];
      *(u32*)(&Gl[b3][0] + (e >> 4) * SG + 2 * (e & 15)) = pG[j];
    }
    if (ts < 32)      ls_eb[b3][ts]      = psc;
    else if (ts < 96) ls_bbf[b][ts - 32] = psc;
  };

  if (w >= 2) { prefetch(0); stage(0, 0); prefetch(1); }
  bar_lds();

  f32x16 Xprev;
  for (int ch = 0; ch < NCH; ++ch) {
    const int cur = ch & 1, c3 = ch % 3;
    // ================= phase A =================
    if (w == 0) {
      // serial engine: W = Khat.S -> B -> U = T.B -> UT
      f32x16 Wacc = mm8(&Kh[cur][0], SbT, lr, lh);
      #pragma unroll
      for (int p = 0; p < 8; ++p) {
        const int i0 = 2 * p, row = rowmap(i0, lh);
        float2 bb0 = ((const float2*)ls_bbf[cur])[row];
        float2 bb1 = ((const float2*)ls_bbf[cur])[row + 1];
        float b0 = bb0.x * vl[cur][row * VS + lr]       - bb0.y * Wacc[i0];
        float b1 = bb1.x * vl[cur][(row + 1) * VS + lr] - bb1.y * Wacc[i0 + 1];
        *(u32*)(Bb + lr * SRU + row) = (u32)f2bf(b0) | ((u32)f2bf(b1) << 16);
      }
      f32x16 Uacc;
      #pragma unroll
      for (int i = 0; i < 16; ++i) Uacc[i] = 0.f;
      #pragma unroll
      for (int kb = 0; kb < 2; ++kb) {
        s16x8 a = *(const s16x8*)(&Tl[cur][0] + lr * SG + 16 * kb + 8 * lh);
        s16x8 b = ld8u(Bb + lr * SRU + 16 * kb + 8 * lh);
        Uacc = __builtin_amdgcn_mfma_f32_32x32x16_bf16(a, b, Uacc, 0, 0, 0);
      }
      #pragma unroll
      for (int p = 0; p < 8; ++p) {
        const int i0 = 2 * p, row = rowmap(i0, lh);
        *(u32*)(&UT[cur][0] + lr * SRU + row) =
            (u32)f2bf(Uacc[i0]) | ((u32)f2bf(Uacc[i0 + 1]) << 16);
      }
    } else if (w == 1) {
      f32x16 Xn = mm8(&Qh[cur][0], SbT, lr, lh);
      if (ch > 0) {   // lagged O for chunk ch-1
        const int pc = (ch - 1) & 1, p3 = (ch - 1) % 3, tp = (ch - 1) * C;
        f32x16 Oacc = Xprev;
        #pragma unroll
        for (int kb = 0; kb < 2; ++kb) {
          s16x8 a = *(const s16x8*)(&Gl[p3][0] + lr * SG + 16 * kb + 8 * lh);
          s16x8 b = ld8u(&UT[pc][0] + lr * SRU + 16 * kb + 8 * lh);
          Oacc = __builtin_amdgcn_mfma_f32_32x32x16_bf16(a, b, Oacc, 0, 0, 0);
        }
        #pragma unroll
        for (int i = 0; i < 16; ++i) {
          const int row = rowmap(i, lh);
          oh[(size_t)(tp + row) * V_ + v0 + lr] = ls_eb[p3][row] * Oacc[i];
        }
      }
      Xprev = Xn;
    } else {
      if (ch + 1 < NCH) stage(cur ^ 1, (ch + 1) % 3);
      if (ch + 2 < NCH) prefetch(ch + 2);
    }
    bar_lds();
    // ================= phase C: state update (all waves) =================
    {
      f32x16 acc = S;
      #pragma unroll
      for (int kb = 0; kb < 2; ++kb) {
        s16x8 a = ld8u(&KhT[cur][0] + (32 * w + lr) * SRT + 16 * kb + 8 * lh);
        s16x8 b = ld8u(&UT[cur][0] + lr * SRU + 16 * kb + 8 * lh);
        acc = __builtin_amdgcn_mfma_f32_32x32x16_bf16(a, b, acc, 0, 0, 0);
      }
      const float ebL = ls_eb[c3][31];
      #pragma unroll
      for (int i = 0; i < 16; i += 2) {
        S[i]     = ebL * acc[i];
        S[i + 1] = ebL * acc[i + 1];
        const int row = rowmap(i, lh);
        *(u32*)(SbT + lr * SK + 32 * w + row) =
            (u32)f2bf(S[i]) | ((u32)f2bf(S[i + 1]) << 16);
      }
    }
    bar_lds();
  }

  // epilogue: O for the last chunk
  if (w == 1) {
    const int pc = (NCH - 1) & 1, p3 = (NCH - 1) % 3, tp = (NCH - 1) * C;
    f32x16 Oacc = Xprev;
    #pragma unroll
    for (int kb = 0; kb < 2; ++kb) {
      s16x8 a = *(const s16x8*)(&Gl[p3][0] + lr * SG + 16 * kb + 8 * lh);
      s16x8 b = ld8u(&UT[pc][0] + lr * SRU + 16 * kb + 8 * lh);
      Oacc = __builtin_amdgcn_mfma_f32_32x32x16_bf16(a, b, Oacc, 0, 0, 0);
    }
    #pragma unroll
    for (int i = 0; i < 16; ++i) {
      const int row = rowmap(i, lh);
      oh[(size_t)(tp + row) * V_ + v0 + lr] = ls_eb[p3][row] * Oacc[i];
    }
  }

  { // final state
    float* sp = out + (size_t)BHn * T_ * V_ + ((size_t)bh * K_ + 32 * w) * V_ + v0 + lr;
    #pragma unroll
    for (int i = 0; i < 16; ++i) sp[(size_t)rowmap(i, lh) * V_] = S[i];
  }
}

extern "C" void kernel_launch(void* const* d_in, const int* in_sizes, int n_in,
                              void* d_out, int out_size, void* d_ws, size_t ws_size,
                              hipStream_t stream) {
  const float* q    = (const float*)d_in[0];
  const float* k    = (const float*)d_in[1];
  const float* v    = (const float*)d_in[2];
  const float* g    = (const float*)d_in[3];
  const float* beta = (const float*)d_in[4];
  const float* s0   = (const float*)d_in[5];
  float* out = (float*)d_out;
  char* ws = (char*)d_ws;   // 64*64*4608 = 18.9 MB
  hipLaunchKernelGGL(gdn_pre_kernel, dim3(BHn * NCH), dim3(256), 0, stream,
                     q, k, g, beta, ws);
  hipLaunchKernelGGL(gdn_seq_kernel, dim3(BHn * NS), dim3(256), 0, stream,
                     q, k, v, s0, ws, out);
}

// Round 9
// 219.897 us; speedup vs baseline: 1.0892x; 1.0892x over previous
//
#include <hip/hip_runtime.h>
#include <math.h>

typedef float f32x16 __attribute__((ext_vector_type(16)));
typedef short s16x8 __attribute__((ext_vector_type(8)));
typedef unsigned int u32;

namespace {
constexpr int B_ = 4, H_ = 16, T_ = 2048, K_ = 128, V_ = 128;
constexpr int BHn = B_ * H_;
constexpr int C = 32;            // chunk length
constexpr int NCH = T_ / C;      // 64 chunks
constexpr int NS = 4;            // V slices (seq pass)
constexpr int VS = V_ / NS;      // 32 cols per block
constexpr float SCALE = 0.08838834764831845f; // 128^-0.5
constexpr int SK = 136;          // ushort stride, [*][128] arrays (16B-aligned rows)
constexpr int SRT = 36;          // ushort stride, KhT [128][32] (72B rows, 2-way-free)
constexpr int SRU = 36;          // ushort stride, UT [32][32]
constexpr int SG = 48;           // ushort stride, Tl/Gl tiles (96B rows)
constexpr int SF = 36;           // f32 stride, pre-pass Mm
constexpr size_t WSCH = 4608;    // ws bytes per (head,chunk): T 2048 | G 2048 | scal 384
}

__device__ __forceinline__ ushort f2bf(float x) {
  unsigned u = __builtin_bit_cast(unsigned, x);
  u += 0x7FFF + ((u >> 16) & 1);       // RNE
  return (ushort)(u >> 16);
}
__device__ __forceinline__ int rowmap(int i, int lh) { return (i & 3) + 8 * (i >> 2) + 4 * lh; }

// barrier waiting only on LDS ops: global loads/stores stay in flight
__device__ __forceinline__ void bar_lds() {
  asm volatile("s_waitcnt lgkmcnt(0)" ::: "memory");
  __builtin_amdgcn_s_barrier();
  asm volatile("" ::: "memory");
}

// 16B fragment from an 8B-aligned LDS row: two b64 loads
__device__ __forceinline__ s16x8 ld8u(const ushort* p) {
  uint2 a = *(const uint2*)(p);
  uint2 b = *(const uint2*)(p + 4);
  int4 r = make_int4((int)a.x, (int)a.y, (int)b.x, (int)b.y);
  return __builtin_bit_cast(s16x8, r);
}

// pack acc (C/D layout: col=lr, row=rowmap(i,lh)) into 8 bf16-pair u32s
__device__ __forceinline__ void packq(const f32x16& a, u32* u) {
  #pragma unroll
  for (int j = 0; j < 4; ++j) {
    u[2*j]   = (u32)f2bf(a[4*j])   | ((u32)f2bf(a[4*j+1]) << 16);
    u[2*j+1] = (u32)f2bf(a[4*j+2]) | ((u32)f2bf(a[4*j+3]) << 16);
  }
}
// acc-layout packs -> MFMA b-operand fragments (col=lane, rows 16kb+8lh+e)
// via cross-half exchange: lh=0 holds row-offsets 0-3 (mod 8), lh=1 holds 4-7.
__device__ __forceinline__ void swapfr(const u32* u, int lh, s16x8& f0, s16x8& f1) {
  u32 e0 = (u32)__shfl_xor((int)(lh ? u[0] : u[2]), 32);
  u32 e1 = (u32)__shfl_xor((int)(lh ? u[1] : u[3]), 32);
  u32 e2 = (u32)__shfl_xor((int)(lh ? u[4] : u[6]), 32);
  u32 e3 = (u32)__shfl_xor((int)(lh ? u[5] : u[7]), 32);
  int4 a0 = lh ? make_int4((int)e0,(int)e1,(int)u[2],(int)u[3])
               : make_int4((int)u[0],(int)u[1],(int)e0,(int)e1);
  int4 a1 = lh ? make_int4((int)e2,(int)e3,(int)u[6],(int)u[7])
               : make_int4((int)u[4],(int)u[5],(int)e2,(int)e3);
  f0 = __builtin_bit_cast(s16x8, a0);
  f1 = __builtin_bit_cast(s16x8, a1);
}

// full-K (128) tile matmul from LDS: A * Barr^T, both stride SK
__device__ __forceinline__ f32x16 mm8(const ushort* A, const ushort* B, int lr, int lh) {
  f32x16 a0, a1;
  #pragma unroll
  for (int i = 0; i < 16; ++i) { a0[i] = 0.f; a1[i] = 0.f; }
  #pragma unroll
  for (int kb = 0; kb < 8; kb += 2) {
    const int o0 = lr * SK + 16 * kb + 8 * lh, o1 = o0 + 16;
    a0 = __builtin_amdgcn_mfma_f32_32x32x16_bf16(*(const s16x8*)(A + o0),
                                                 *(const s16x8*)(B + o0), a0, 0, 0, 0);
    a1 = __builtin_amdgcn_mfma_f32_32x32x16_bf16(*(const s16x8*)(A + o1),
                                                 *(const s16x8*)(B + o1), a1, 0, 0, 0);
  }
  return a0 + a1;
}

// ============ pass 1: chunk-local precompute (4096 independent blocks) ============
__global__ __launch_bounds__(256, 2)
void gdn_pre_kernel(const float* __restrict__ qg, const float* __restrict__ kg,
                    const float* __restrict__ gg, const float* __restrict__ bg,
                    char* __restrict__ ws)
{
  const int bid = blockIdx.x;
  const int bh = bid >> 6, ch = bid & 63;
  const int t = threadIdx.x, w = t >> 6, l = t & 63, lr = l & 31, lh = l >> 5;
  const int r8 = t >> 3, c8 = t & 7;
  const int t0 = ch * C;

  __shared__ __align__(16) ushort Kh[C * SK], Qh[C * SK];
  __shared__ __align__(16) float Mm[C * SF];
  __shared__ __align__(16) ushort Tt[C * 32], Gt[C * 32];
  __shared__ float ls_g[C], ls_b[C], ls_eb[C], ls_emb[C];

  { // stage + normalize q,k
    const float4* q4 = (const float4*)(qg + ((size_t)bh * T_ + t0 + r8) * K_);
    const float4* k4 = (const float4*)(kg + ((size_t)bh * T_ + t0 + r8) * K_);
    float4 qv[4], kv[4]; float sq = 0.f, sk = 0.f;
    #pragma unroll
    for (int c = 0; c < 4; ++c) {
      qv[c] = q4[c8 + 8 * c]; kv[c] = k4[c8 + 8 * c];
      sq += qv[c].x*qv[c].x + qv[c].y*qv[c].y + qv[c].z*qv[c].z + qv[c].w*qv[c].w;
      sk += kv[c].x*kv[c].x + kv[c].y*kv[c].y + kv[c].z*kv[c].z + kv[c].w*kv[c].w;
    }
    sq += __shfl_xor(sq, 1); sq += __shfl_xor(sq, 2); sq += __shfl_xor(sq, 4);
    sk += __shfl_xor(sk, 1); sk += __shfl_xor(sk, 2); sk += __shfl_xor(sk, 4);
    const float niq = SCALE / fmaxf(sqrtf(sq), 1e-12f);
    const float nik = 1.0f / fmaxf(sqrtf(sk), 1e-12f);
    #pragma unroll
    for (int c = 0; c < 4; ++c) {
      const int f4 = c8 + 8 * c;
      uint2 upk, upq;
      upk.x = (u32)f2bf(kv[c].x*nik) | ((u32)f2bf(kv[c].y*nik) << 16);
      upk.y = (u32)f2bf(kv[c].z*nik) | ((u32)f2bf(kv[c].w*nik) << 16);
      upq.x = (u32)f2bf(qv[c].x*niq) | ((u32)f2bf(qv[c].y*niq) << 16);
      upq.y = (u32)f2bf(qv[c].z*niq) | ((u32)f2bf(qv[c].w*niq) << 16);
      *(uint2*)(Kh + r8 * SK + f4 * 4) = upk;
      *(uint2*)(Qh + r8 * SK + f4 * 4) = upq;
    }
    if (t < C)          ls_g[t]     = gg[(size_t)bh * T_ + t0 + t];
    else if (t < 2 * C) ls_b[t - C] = bg[(size_t)bh * T_ + t0 + t - C];
  }
  __syncthreads();
  if (w == 3 && l < 32) {   // inclusive prefix of g
    float x = ls_g[l];
    #pragma unroll
    for (int d = 1; d < 32; d <<= 1) { float y = __shfl_up(x, d); if (l >= d) x += y; }
    ls_eb[l] = expf(x); ls_emb[l] = expf(-x);
  }
  if (w == 0) {
    f32x16 acc = mm8(Kh, Kh, lr, lh);
    #pragma unroll
    for (int i = 0; i < 16; ++i) Mm[rowmap(i, lh) * SF + lr] = acc[i];
  }
  if (w == 1) {
    f32x16 acc = mm8(Qh, Kh, lr, lh);
    #pragma unroll
    for (int i = 0; i < 16; ++i) {
      int row = rowmap(i, lh);
      Gt[row * 32 + lr] = (lr <= row) ? f2bf(acc[i]) : (ushort)0;
    }
  }
  __syncthreads();
  if (w == 2 && l < 32) {   // T = (I + tril_strict(diag(b) M))^-1, column l
    const int j = l;
    float x[32];
    #pragma unroll
    for (int m = 0; m < 32; ++m) x[m] = (m == j) ? 1.f : 0.f;
    #pragma unroll
    for (int r = 1; r < 32; ++r) {
      const float* mr = Mm + r * SF;
      float p0 = 0.f, p1 = 0.f, p2 = 0.f, p3 = 0.f;
      #pragma unroll
      for (int jb = 0; jb + 4 <= r; jb += 4) {
        float4 m4 = *(const float4*)(mr + jb);
        p0 = fmaf(m4.x, x[jb + 0], p0);
        p1 = fmaf(m4.y, x[jb + 1], p1);
        p2 = fmaf(m4.z, x[jb + 2], p2);
        p3 = fmaf(m4.w, x[jb + 3], p3);
      }
      #pragma unroll
      for (int m = (r & ~3); m < r; ++m) p1 = fmaf(mr[m], x[m], p1);
      float xr = -ls_b[r] * ((p0 + p1) + (p2 + p3));
      if (r > j) x[r] = xr;
    }
    #pragma unroll
    for (int r = 0; r < 32; ++r) Tt[r * 32 + j] = f2bf(x[r]);
  }
  __syncthreads();
  { // copy to ws  (scal: eb[32] | interleaved (bev,bet)[32] pairs)
    char* wsb = ws + ((size_t)bh * NCH + ch) * WSCH;
    u32* wT = (u32*)wsb; u32* wG = (u32*)(wsb + 2048); float* wS = (float*)(wsb + 4096);
    const u32* sT = (const u32*)Tt; const u32* sG = (const u32*)Gt;
    wT[t] = sT[t]; wT[t + 256] = sT[t + 256];
    wG[t] = sG[t]; wG[t + 256] = sG[t + 256];
    if (t < 32)      wS[t] = ls_eb[t];
    else if (t < 96) {
      int j = t - 32, r = j >> 1;
      wS[t] = (j & 1) ? ls_b[r] : ls_b[r] * ls_emb[r];
    }
  }
}

// ============ pass 2: sequential scan (256 blocks, 1 barrier/chunk) ============
__global__ __launch_bounds__(256, 1)
void gdn_seq_kernel(const float* __restrict__ qg, const float* __restrict__ kg,
                    const float* __restrict__ vg, const float* __restrict__ s0,
                    const char* __restrict__ ws, float* __restrict__ out)
{
  const int bid = blockIdx.x;
  const int xcd = bid & 7, qd = bid >> 3;
  const int bh = (qd >> 2) * 8 + xcd;
  const int v0 = (qd & 3) * VS;
  const int t = threadIdx.x, w = t >> 6, l = t & 63, lr = l & 31, lh = l >> 5;
  const int ts = t & 127;               // stager index (w>=2)
  const int r4 = ts >> 2, c4 = ts & 3;

  __shared__ __align__(16) ushort Kh[2][C * SK], Qh[2][C * SK];
  __shared__ __align__(16) ushort KhT[2][K_ * SRT];
  __shared__ __align__(16) ushort Tl[2][C * SG], Gl[3][C * SG];
  __shared__ __align__(16) float  vl[2][C * VS];
  __shared__ __align__(16) float  ls_eb[3][C];
  __shared__ __align__(16) float  ls_bbf[2][2 * C];   // interleaved (bev,bet)
  __shared__ __align__(16) ushort UT[2][32 * SRU];
  __shared__ __align__(16) ushort SbT[2][32 * SK];    // bf16 S^T [v][k], dbuf

  const float* qh = qg + (size_t)bh * T_ * K_;
  const float* kh = kg + (size_t)bh * T_ * K_;
  const float* vh = vg + (size_t)bh * T_ * V_;
  const char* wsh = ws + (size_t)bh * NCH * WSCH;
  float* oh = out + (size_t)bh * T_ * V_;

  // ---- w0: full state in registers (4 quadrants x f32x16) ----
  f32x16 Sst[4];
  s16x8 Sfrag[8];            // bf16 S^T b-operand fragments (kb = 0..7)
  if (w == 0) {
    #pragma unroll
    for (int q = 0; q < 4; ++q) {
      const float* sp = s0 + ((size_t)bh * K_ + 32 * q) * V_ + v0 + lr;
      #pragma unroll
      for (int i = 0; i < 16; i += 2) {
        int row = rowmap(i, lh);
        Sst[q][i]     = sp[(size_t)row * V_];
        Sst[q][i + 1] = sp[(size_t)(row + 1) * V_];
      }
      u32 us[8]; packq(Sst[q], us);
      #pragma unroll
      for (int p = 0; p < 8; ++p)
        *(u32*)(&SbT[0][0] + lr * SK + 32 * q + rowmap(2 * p, lh)) = us[p];
      swapfr(us, lh, Sfrag[2 * q], Sfrag[2 * q + 1]);
    }
  }

  // ---- stagers ----
  float4 pq[8], pk[8], pv[2];
  u32 pT[4], pG[4]; float psc = 0.f;
  auto prefetch = [&](int cc) {
    const float4* q4 = (const float4*)(qh + (size_t)(cc * C + r4) * K_);
    const float4* k4 = (const float4*)(kh + (size_t)(cc * C + r4) * K_);
    #pragma unroll
    for (int j = 0; j < 8; ++j) { pq[j] = q4[c4 + 4 * j]; pk[j] = k4[c4 + 4 * j]; }
    const float4* v4 = (const float4*)(vh + (size_t)(cc * C + r4) * V_ + v0);
    pv[0] = v4[c4]; pv[1] = v4[c4 + 4];
    const char* wsb = wsh + (size_t)cc * WSCH;
    #pragma unroll
    for (int j = 0; j < 4; ++j) {
      pT[j] = ((const u32*)wsb)[ts + 128 * j];
      pG[j] = ((const u32*)(wsb + 2048))[ts + 128 * j];
    }
    psc = (ts < 96) ? ((const float*)(wsb + 4096))[ts] : 0.f;
  };
  auto stage = [&](int b, int b3) {
    float sq = 0.f, sk = 0.f;
    #pragma unroll
    for (int j = 0; j < 8; ++j) {
      sq += pq[j].x*pq[j].x + pq[j].y*pq[j].y + pq[j].z*pq[j].z + pq[j].w*pq[j].w;
      sk += pk[j].x*pk[j].x + pk[j].y*pk[j].y + pk[j].z*pk[j].z + pk[j].w*pk[j].w;
    }
    sq += __shfl_xor(sq, 1); sq += __shfl_xor(sq, 2);
    sk += __shfl_xor(sk, 1); sk += __shfl_xor(sk, 2);
    const float niq = SCALE / fmaxf(sqrtf(sq), 1e-12f);
    const float nik = 1.0f / fmaxf(sqrtf(sk), 1e-12f);
    #pragma unroll
    for (int j = 0; j < 8; ++j) {
      const int f4 = c4 + 4 * j;
      ushort k0 = f2bf(pk[j].x * nik), k1 = f2bf(pk[j].y * nik);
      ushort k2 = f2bf(pk[j].z * nik), k3 = f2bf(pk[j].w * nik);
      uint2 upk, upq;
      upk.x = (u32)k0 | ((u32)k1 << 16);
      upk.y = (u32)k2 | ((u32)k3 << 16);
      upq.x = (u32)f2bf(pq[j].x * niq) | ((u32)f2bf(pq[j].y * niq) << 16);
      upq.y = (u32)f2bf(pq[j].z * niq) | ((u32)f2bf(pq[j].w * niq) << 16);
      *(uint2*)(&Kh[b][0] + r4 * SK + 4 * f4) = upk;
      *(uint2*)(&Qh[b][0] + r4 * SK + 4 * f4) = upq;
      ushort* kt = &KhT[b][0] + (4 * f4) * SRT + r4;
      kt[0] = k0; kt[SRT] = k1; kt[2 * SRT] = k2; kt[3 * SRT] = k3;
    }
    *(float4*)(&vl[b][0] + r4 * VS + 4 * c4) = pv[0];
    *(float4*)(&vl[b][0] + r4 * VS + 4 * (c4 + 4)) = pv[1];
    #pragma unroll
    for (int j = 0; j < 4; ++j) {
      int e = ts + 128 * j;
      *(u32*)(&Tl[b][0]  + (e >> 4) * SG + 2 * (e & 15)) = pT[j];
      *(u32*)(&Gl[b3][0] + (e >> 4) * SG + 2 * (e & 15)) = pG[j];
    }
    if (ts < 32)      ls_eb[b3][ts]      = psc;
    else if (ts < 96) ls_bbf[b][ts - 32] = psc;
  };

  if (w >= 2) { prefetch(0); stage(0, 0); prefetch(1); }
  bar_lds();

  f32x16 Xprev;
  for (int ch = 0; ch < NCH; ++ch) {
    const int cur = ch & 1, nxt = cur ^ 1, c3 = ch % 3;
    if (w == 0) {
      // ---- serial engine, all in-register ----
      f32x16 a0, a1;
      #pragma unroll
      for (int i = 0; i < 16; ++i) { a0[i] = 0.f; a1[i] = 0.f; }
      #pragma unroll
      for (int kb = 0; kb < 8; kb += 2) {
        s16x8 ka = *(const s16x8*)(&Kh[cur][0] + lr * SK + 16 * kb + 8 * lh);
        s16x8 kbv = *(const s16x8*)(&Kh[cur][0] + lr * SK + 16 * (kb + 1) + 8 * lh);
        a0 = __builtin_amdgcn_mfma_f32_32x32x16_bf16(ka, Sfrag[kb], a0, 0, 0, 0);
        a1 = __builtin_amdgcn_mfma_f32_32x32x16_bf16(kbv, Sfrag[kb + 1], a1, 0, 0, 0);
      }
      f32x16 Wacc = a0 + a1;
      f32x16 Bv;
      #pragma unroll
      for (int i = 0; i < 16; ++i) {
        int row = rowmap(i, lh);
        float2 bb = ((const float2*)ls_bbf[cur])[row];
        Bv[i] = bb.x * vl[cur][row * VS + lr] - bb.y * Wacc[i];
      }
      u32 ub[8]; packq(Bv, ub);
      s16x8 bf0, bf1; swapfr(ub, lh, bf0, bf1);
      f32x16 Uacc;
      #pragma unroll
      for (int i = 0; i < 16; ++i) Uacc[i] = 0.f;
      {
        s16x8 t0f = *(const s16x8*)(&Tl[cur][0] + lr * SG + 8 * lh);
        s16x8 t1f = *(const s16x8*)(&Tl[cur][0] + lr * SG + 16 + 8 * lh);
        Uacc = __builtin_amdgcn_mfma_f32_32x32x16_bf16(t0f, bf0, Uacc, 0, 0, 0);
        Uacc = __builtin_amdgcn_mfma_f32_32x32x16_bf16(t1f, bf1, Uacc, 0, 0, 0);
      }
      u32 uu[8]; packq(Uacc, uu);
      #pragma unroll
      for (int p = 0; p < 8; ++p)
        *(u32*)(&UT[cur][0] + lr * SRU + rowmap(2 * p, lh)) = uu[p];
      s16x8 uf0, uf1; swapfr(uu, lh, uf0, uf1);
      const float ebL = ls_eb[c3][31];
      #pragma unroll
      for (int q = 0; q < 4; ++q) {
        f32x16 acc = Sst[q];
        s16x8 ka0 = ld8u(&KhT[cur][0] + (32 * q + lr) * SRT + 8 * lh);
        s16x8 ka1 = ld8u(&KhT[cur][0] + (32 * q + lr) * SRT + 16 + 8 * lh);
        acc = __builtin_amdgcn_mfma_f32_32x32x16_bf16(ka0, uf0, acc, 0, 0, 0);
        acc = __builtin_amdgcn_mfma_f32_32x32x16_bf16(ka1, uf1, acc, 0, 0, 0);
        #pragma unroll
        for (int i = 0; i < 16; ++i) Sst[q][i] = ebL * acc[i];
        u32 us[8]; packq(Sst[q], us);
        #pragma unroll
        for (int p = 0; p < 8; ++p)
          *(u32*)(&SbT[nxt][0] + lr * SK + 32 * q + rowmap(2 * p, lh)) = us[p];
        swapfr(us, lh, Sfrag[2 * q], Sfrag[2 * q + 1]);
      }
    } else if (w == 1) {
      f32x16 Xn = mm8(&Qh[cur][0], &SbT[cur][0], lr, lh);
      if (ch > 0) {   // lagged O for chunk ch-1
        const int pc = (ch - 1) & 1, p3 = (ch - 1) % 3, tp = (ch - 1) * C;
        f32x16 Oacc = Xprev;
        #pragma unroll
        for (int kb = 0; kb < 2; ++kb) {
          s16x8 a = *(const s16x8*)(&Gl[p3][0] + lr * SG + 16 * kb + 8 * lh);
          s16x8 b = ld8u(&UT[pc][0] + lr * SRU + 16 * kb + 8 * lh);
          Oacc = __builtin_amdgcn_mfma_f32_32x32x16_bf16(a, b, Oacc, 0, 0, 0);
        }
        #pragma unroll
        for (int i = 0; i < 16; ++i) {
          const int row = rowmap(i, lh);
          oh[(size_t)(tp + row) * V_ + v0 + lr] = ls_eb[p3][row] * Oacc[i];
        }
      }
      Xprev = Xn;
    } else {
      if (ch + 1 < NCH) stage(nxt, (ch + 1) % 3);
      if (ch + 2 < NCH) prefetch(ch + 2);
    }
    bar_lds();
  }

  // epilogue: O for the last chunk
  if (w == 1) {
    const int pc = (NCH - 1) & 1, p3 = (NCH - 1) % 3, tp = (NCH - 1) * C;
    f32x16 Oacc = Xprev;
    #pragma unroll
    for (int kb = 0; kb < 2; ++kb) {
      s16x8 a = *(const s16x8*)(&Gl[p3][0] + lr * SG + 16 * kb + 8 * lh);
      s16x8 b = ld8u(&UT[pc][0] + lr * SRU + 16 * kb + 8 * lh);
      Oacc = __builtin_amdgcn_mfma_f32_32x32x16_bf16(a, b, Oacc, 0, 0, 0);
    }
    #pragma unroll
    for (int i = 0; i < 16; ++i) {
      const int row = rowmap(i, lh);
      oh[(size_t)(tp + row) * V_ + v0 + lr] = ls_eb[p3][row] * Oacc[i];
    }
  }
  // final state from w0 registers
  if (w == 0) {
    #pragma unroll
    for (int q = 0; q < 4; ++q) {
      float* sp = out + (size_t)BHn * T_ * V_
                      + ((size_t)bh * K_ + 32 * q) * V_ + v0 + lr;
      #pragma unroll
      for (int i = 0; i < 16; ++i)
        sp[(size_t)rowmap(i, lh) * V_] = Sst[q][i];
    }
  }
}

extern "C" void kernel_launch(void* const* d_in, const int* in_sizes, int n_in,
                              void* d_out, int out_size, void* d_ws, size_t ws_size,
                              hipStream_t stream) {
  const float* q    = (const float*)d_in[0];
  const float* k    = (const float*)d_in[1];
  const float* v    = (const float*)d_in[2];
  const float* g    = (const float*)d_in[3];
  const float* beta = (const float*)d_in[4];
  const float* s0   = (const float*)d_in[5];
  float* out = (float*)d_out;
  char* ws = (char*)d_ws;   // 64*64*4608 = 18.9 MB
  hipLaunchKernelGGL(gdn_pre_kernel, dim3(BHn * NCH), dim3(256), 0, stream,
                     q, k, g, beta, ws);
  hipLaunchKernelGGL(gdn_seq_kernel, dim3(BHn * NS), dim3(256), 0, stream,
                     q, k, v, s0, ws, out);
}

// Round 10
// 206.911 us; speedup vs baseline: 1.1575x; 1.0628x over previous
//
#include <hip/hip_runtime.h>
#include <math.h>

typedef float f32x16 __attribute__((ext_vector_type(16)));
typedef short s16x8 __attribute__((ext_vector_type(8)));
typedef unsigned int u32;

namespace {
constexpr int B_ = 4, H_ = 16, T_ = 2048, K_ = 128, V_ = 128;
constexpr int BHn = B_ * H_;
constexpr int C = 32;            // chunk length
constexpr int NCH = T_ / C;      // 64 chunks
constexpr int NS = 4;            // V slices (seq pass)
constexpr int VS = V_ / NS;      // 32 cols per block
constexpr float SCALE = 0.08838834764831845f; // 128^-0.5
constexpr int SK = 136;          // ushort stride, [*][128] arrays (16B-aligned rows)
constexpr int SRT = 36;          // ushort stride, KhT [128][32] (72B rows, 2-way-free)
constexpr int SRU = 36;          // ushort stride, UT [32][32]
constexpr int SG = 48;           // ushort stride, Tl/Gl tiles (96B rows)
constexpr int SF = 36;           // f32 stride, pre-pass Mm
constexpr size_t WSCH = 4608;    // ws bytes per (head,chunk): T 2048 | G 2048 | scal 384
}

__device__ __forceinline__ ushort f2bf(float x) {
  unsigned u = __builtin_bit_cast(unsigned, x);
  u += 0x7FFF + ((u >> 16) & 1);       // RNE
  return (ushort)(u >> 16);
}
// packed bf16 pair via HW instruction (RNE, same as f2bf): lo->bits0-15, hi->bits16-31
__device__ __forceinline__ u32 cvtpk(float lo, float hi) {
  u32 r;
  asm("v_cvt_pk_bf16_f32 %0, %1, %2" : "=v"(r) : "v"(lo), "v"(hi));
  return r;
}
__device__ __forceinline__ int rowmap(int i, int lh) { return (i & 3) + 8 * (i >> 2) + 4 * lh; }

// barrier waiting only on LDS ops: global loads/stores stay in flight
__device__ __forceinline__ void bar_lds() {
  asm volatile("s_waitcnt lgkmcnt(0)" ::: "memory");
  __builtin_amdgcn_s_barrier();
  asm volatile("" ::: "memory");
}

// 16B fragment from an 8B-aligned LDS row: two b64 loads
__device__ __forceinline__ s16x8 ld8u(const ushort* p) {
  uint2 a = *(const uint2*)(p);
  uint2 b = *(const uint2*)(p + 4);
  int4 r = make_int4((int)a.x, (int)a.y, (int)b.x, (int)b.y);
  return __builtin_bit_cast(s16x8, r);
}

// pack acc (C/D layout: col=lr, row=rowmap(i,lh)) into 8 bf16-pair u32s
__device__ __forceinline__ void packq(const f32x16& a, u32* u) {
  #pragma unroll
  for (int j = 0; j < 4; ++j) {
    u[2*j]   = cvtpk(a[4*j],     a[4*j+1]);
    u[2*j+1] = cvtpk(a[4*j+2],   a[4*j+3]);
  }
}
// acc-layout packs -> MFMA b-operand fragments via v_permlane32_swap_b32:
// swap(a,b): a' = (lo: own a, hi: partner b), b' = (lo: partner a, hi: own b)
// which are exactly fragment words {0,2} for pair (u0,u2), {1,3} for (u1,u3).
__device__ __forceinline__ void swapfr(const u32* u, s16x8& f0, s16x8& f1) {
  u32 a0 = u[0], b0 = u[2], a1 = u[1], b1 = u[3];
  u32 a2 = u[4], b2 = u[6], a3 = u[5], b3 = u[7];
  asm("v_permlane32_swap_b32 %0, %1" : "+v"(a0), "+v"(b0));
  asm("v_permlane32_swap_b32 %0, %1" : "+v"(a1), "+v"(b1));
  asm("v_permlane32_swap_b32 %0, %1" : "+v"(a2), "+v"(b2));
  asm("v_permlane32_swap_b32 %0, %1" : "+v"(a3), "+v"(b3));
  f0 = __builtin_bit_cast(s16x8, make_int4((int)a0, (int)a1, (int)b0, (int)b1));
  f1 = __builtin_bit_cast(s16x8, make_int4((int)a2, (int)a3, (int)b2, (int)b3));
}

// full-K (128) tile matmul from LDS: A * Barr^T, both stride SK
__device__ __forceinline__ f32x16 mm8(const ushort* A, const ushort* B, int lr, int lh) {
  f32x16 a0, a1;
  #pragma unroll
  for (int i = 0; i < 16; ++i) { a0[i] = 0.f; a1[i] = 0.f; }
  #pragma unroll
  for (int kb = 0; kb < 8; kb += 2) {
    const int o0 = lr * SK + 16 * kb + 8 * lh, o1 = o0 + 16;
    a0 = __builtin_amdgcn_mfma_f32_32x32x16_bf16(*(const s16x8*)(A + o0),
                                                 *(const s16x8*)(B + o0), a0, 0, 0, 0);
    a1 = __builtin_amdgcn_mfma_f32_32x32x16_bf16(*(const s16x8*)(A + o1),
                                                 *(const s16x8*)(B + o1), a1, 0, 0, 0);
  }
  return a0 + a1;
}

// ============ pass 1: chunk-local precompute (4096 independent blocks) ============
__global__ __launch_bounds__(256, 2)
void gdn_pre_kernel(const float* __restrict__ qg, const float* __restrict__ kg,
                    const float* __restrict__ gg, const float* __restrict__ bg,
                    char* __restrict__ ws)
{
  const int bid = blockIdx.x;
  const int bh = bid >> 6, ch = bid & 63;
  const int t = threadIdx.x, w = t >> 6, l = t & 63, lr = l & 31, lh = l >> 5;
  const int r8 = t >> 3, c8 = t & 7;
  const int t0 = ch * C;

  __shared__ __align__(16) ushort Kh[C * SK], Qh[C * SK];
  __shared__ __align__(16) float Mm[C * SF];
  __shared__ __align__(16) ushort Tt[C * 32], Gt[C * 32];
  __shared__ float ls_g[C], ls_b[C], ls_eb[C], ls_emb[C];

  { // stage + normalize q,k
    const float4* q4 = (const float4*)(qg + ((size_t)bh * T_ + t0 + r8) * K_);
    const float4* k4 = (const float4*)(kg + ((size_t)bh * T_ + t0 + r8) * K_);
    float4 qv[4], kv[4]; float sq = 0.f, sk = 0.f;
    #pragma unroll
    for (int c = 0; c < 4; ++c) {
      qv[c] = q4[c8 + 8 * c]; kv[c] = k4[c8 + 8 * c];
      sq += qv[c].x*qv[c].x + qv[c].y*qv[c].y + qv[c].z*qv[c].z + qv[c].w*qv[c].w;
      sk += kv[c].x*kv[c].x + kv[c].y*kv[c].y + kv[c].z*kv[c].z + kv[c].w*kv[c].w;
    }
    sq += __shfl_xor(sq, 1); sq += __shfl_xor(sq, 2); sq += __shfl_xor(sq, 4);
    sk += __shfl_xor(sk, 1); sk += __shfl_xor(sk, 2); sk += __shfl_xor(sk, 4);
    const float niq = SCALE / fmaxf(sqrtf(sq), 1e-12f);
    const float nik = 1.0f / fmaxf(sqrtf(sk), 1e-12f);
    #pragma unroll
    for (int c = 0; c < 4; ++c) {
      const int f4 = c8 + 8 * c;
      uint2 upk, upq;
      upk.x = cvtpk(kv[c].x * nik, kv[c].y * nik);
      upk.y = cvtpk(kv[c].z * nik, kv[c].w * nik);
      upq.x = cvtpk(qv[c].x * niq, qv[c].y * niq);
      upq.y = cvtpk(qv[c].z * niq, qv[c].w * niq);
      *(uint2*)(Kh + r8 * SK + f4 * 4) = upk;
      *(uint2*)(Qh + r8 * SK + f4 * 4) = upq;
    }
    if (t < C)          ls_g[t]     = gg[(size_t)bh * T_ + t0 + t];
    else if (t < 2 * C) ls_b[t - C] = bg[(size_t)bh * T_ + t0 + t - C];
  }
  __syncthreads();
  if (w == 3 && l < 32) {   // inclusive prefix of g
    float x = ls_g[l];
    #pragma unroll
    for (int d = 1; d < 32; d <<= 1) { float y = __shfl_up(x, d); if (l >= d) x += y; }
    ls_eb[l] = expf(x); ls_emb[l] = expf(-x);
  }
  if (w == 0) {
    f32x16 acc = mm8(Kh, Kh, lr, lh);
    #pragma unroll
    for (int i = 0; i < 16; ++i) Mm[rowmap(i, lh) * SF + lr] = acc[i];
  }
  if (w == 1) {
    f32x16 acc = mm8(Qh, Kh, lr, lh);
    #pragma unroll
    for (int i = 0; i < 16; ++i) {
      int row = rowmap(i, lh);
      Gt[row * 32 + lr] = (lr <= row) ? f2bf(acc[i]) : (ushort)0;
    }
  }
  __syncthreads();
  if (w == 2 && l < 32) {   // T = (I + tril_strict(diag(b) M))^-1, column l
    const int j = l;
    float x[32];
    #pragma unroll
    for (int m = 0; m < 32; ++m) x[m] = (m == j) ? 1.f : 0.f;
    #pragma unroll
    for (int r = 1; r < 32; ++r) {
      const float* mr = Mm + r * SF;
      float p0 = 0.f, p1 = 0.f, p2 = 0.f, p3 = 0.f;
      #pragma unroll
      for (int jb = 0; jb + 4 <= r; jb += 4) {
        float4 m4 = *(const float4*)(mr + jb);
        p0 = fmaf(m4.x, x[jb + 0], p0);
        p1 = fmaf(m4.y, x[jb + 1], p1);
        p2 = fmaf(m4.z, x[jb + 2], p2);
        p3 = fmaf(m4.w, x[jb + 3], p3);
      }
      #pragma unroll
      for (int m = (r & ~3); m < r; ++m) p1 = fmaf(mr[m], x[m], p1);
      float xr = -ls_b[r] * ((p0 + p1) + (p2 + p3));
      if (r > j) x[r] = xr;
    }
    #pragma unroll
    for (int r = 0; r < 32; ++r) Tt[r * 32 + j] = f2bf(x[r]);
  }
  __syncthreads();
  { // copy to ws  (scal: eb[32] | interleaved (bev,bet)[32] pairs)
    char* wsb = ws + ((size_t)bh * NCH + ch) * WSCH;
    u32* wT = (u32*)wsb; u32* wG = (u32*)(wsb + 2048); float* wS = (float*)(wsb + 4096);
    const u32* sT = (const u32*)Tt; const u32* sG = (const u32*)Gt;
    wT[t] = sT[t]; wT[t + 256] = sT[t + 256];
    wG[t] = sG[t]; wG[t + 256] = sG[t + 256];
    if (t < 32)      wS[t] = ls_eb[t];
    else if (t < 96) {
      int j = t - 32, r = j >> 1;
      wS[t] = (j & 1) ? ls_b[r] : ls_b[r] * ls_emb[r];
    }
  }
}

// ============ pass 2: sequential scan (256 blocks, 1 barrier/chunk) ============
__global__ __launch_bounds__(256, 1)
void gdn_seq_kernel(const float* __restrict__ qg, const float* __restrict__ kg,
                    const float* __restrict__ vg, const float* __restrict__ s0,
                    const char* __restrict__ ws, float* __restrict__ out)
{
  const int bid = blockIdx.x;
  const int xcd = bid & 7, qd = bid >> 3;
  const int bh = (qd >> 2) * 8 + xcd;
  const int v0 = (qd & 3) * VS;
  const int t = threadIdx.x, w = t >> 6, l = t & 63, lr = l & 31, lh = l >> 5;
  const int ts = t & 127;               // stager index (w>=2)
  const int r4 = ts >> 2, c4 = ts & 3;

  __shared__ __align__(16) ushort Kh[2][C * SK], Qh[2][C * SK];
  __shared__ __align__(16) ushort KhT[2][K_ * SRT];
  __shared__ __align__(16) ushort Tl[2][C * SG], Gl[3][C * SG];
  __shared__ __align__(16) float  vl[2][C * VS];
  __shared__ __align__(16) float  ls_eb[3][C];
  __shared__ __align__(16) float  ls_bbf[2][2 * C];   // interleaved (bev,bet)
  __shared__ __align__(16) ushort UT[2][32 * SRU];
  __shared__ __align__(16) ushort SbT[2][32 * SK];    // bf16 S^T [v][k], dbuf

  const float* qh = qg + (size_t)bh * T_ * K_;
  const float* kh = kg + (size_t)bh * T_ * K_;
  const float* vh = vg + (size_t)bh * T_ * V_;
  const char* wsh = ws + (size_t)bh * NCH * WSCH;
  float* oh = out + (size_t)bh * T_ * V_;

  // ---- w0: full state in registers (4 quadrants x f32x16) ----
  f32x16 Sst[4];
  s16x8 Sfrag[8];            // bf16 S^T b-operand fragments (kb = 0..7)
  if (w == 0) {
    #pragma unroll
    for (int q = 0; q < 4; ++q) {
      const float* sp = s0 + ((size_t)bh * K_ + 32 * q) * V_ + v0 + lr;
      #pragma unroll
      for (int i = 0; i < 16; i += 2) {
        int row = rowmap(i, lh);
        Sst[q][i]     = sp[(size_t)row * V_];
        Sst[q][i + 1] = sp[(size_t)(row + 1) * V_];
      }
      u32 us[8]; packq(Sst[q], us);
      #pragma unroll
      for (int p = 0; p < 8; ++p)
        *(u32*)(&SbT[0][0] + lr * SK + 32 * q + rowmap(2 * p, lh)) = us[p];
      swapfr(us, Sfrag[2 * q], Sfrag[2 * q + 1]);
    }
  }

  // ---- stagers ----
  float4 pq[8], pk[8], pv[2];
  u32 pT[4], pG[4]; float psc = 0.f;
  auto prefetch = [&](int cc) {
    const float4* q4 = (const float4*)(qh + (size_t)(cc * C + r4) * K_);
    const float4* k4 = (const float4*)(kh + (size_t)(cc * C + r4) * K_);
    #pragma unroll
    for (int j = 0; j < 8; ++j) { pq[j] = q4[c4 + 4 * j]; pk[j] = k4[c4 + 4 * j]; }
    const float4* v4 = (const float4*)(vh + (size_t)(cc * C + r4) * V_ + v0);
    pv[0] = v4[c4]; pv[1] = v4[c4 + 4];
    const char* wsb = wsh + (size_t)cc * WSCH;
    #pragma unroll
    for (int j = 0; j < 4; ++j) {
      pT[j] = ((const u32*)wsb)[ts + 128 * j];
      pG[j] = ((const u32*)(wsb + 2048))[ts + 128 * j];
    }
    psc = (ts < 96) ? ((const float*)(wsb + 4096))[ts] : 0.f;
  };
  auto stage = [&](int b, int b3) {
    float sq = 0.f, sk = 0.f;
    #pragma unroll
    for (int j = 0; j < 8; ++j) {
      sq += pq[j].x*pq[j].x + pq[j].y*pq[j].y + pq[j].z*pq[j].z + pq[j].w*pq[j].w;
      sk += pk[j].x*pk[j].x + pk[j].y*pk[j].y + pk[j].z*pk[j].z + pk[j].w*pk[j].w;
    }
    sq += __shfl_xor(sq, 1); sq += __shfl_xor(sq, 2);
    sk += __shfl_xor(sk, 1); sk += __shfl_xor(sk, 2);
    const float niq = SCALE / fmaxf(sqrtf(sq), 1e-12f);
    const float nik = 1.0f / fmaxf(sqrtf(sk), 1e-12f);
    #pragma unroll
    for (int j = 0; j < 8; ++j) {
      const int f4 = c4 + 4 * j;
      uint2 upk, upq;
      upk.x = cvtpk(pk[j].x * nik, pk[j].y * nik);
      upk.y = cvtpk(pk[j].z * nik, pk[j].w * nik);
      upq.x = cvtpk(pq[j].x * niq, pq[j].y * niq);
      upq.y = cvtpk(pq[j].z * niq, pq[j].w * niq);
      *(uint2*)(&Kh[b][0] + r4 * SK + 4 * f4) = upk;
      *(uint2*)(&Qh[b][0] + r4 * SK + 4 * f4) = upq;
      ushort* kt = &KhT[b][0] + (4 * f4) * SRT + r4;
      kt[0]       = (ushort)upk.x;
      kt[SRT]     = (ushort)(upk.x >> 16);
      kt[2 * SRT] = (ushort)upk.y;
      kt[3 * SRT] = (ushort)(upk.y >> 16);
    }
    *(float4*)(&vl[b][0] + r4 * VS + 4 * c4) = pv[0];
    *(float4*)(&vl[b][0] + r4 * VS + 4 * (c4 + 4)) = pv[1];
    #pragma unroll
    for (int j = 0; j < 4; ++j) {
      int e = ts + 128 * j;
      *(u32*)(&Tl[b][0]  + (e >> 4) * SG + 2 * (e & 15)) = pT[j];
      *(u32*)(&Gl[b3][0] + (e >> 4) * SG + 2 * (e & 15)) = pG[j];
    }
    if (ts < 32)      ls_eb[b3][ts]      = psc;
    else if (ts < 96) ls_bbf[b][ts - 32] = psc;
  };

  if (w >= 2) { prefetch(0); stage(0, 0); prefetch(1); }
  bar_lds();

  f32x16 Xprev;
  for (int ch = 0; ch < NCH; ++ch) {
    const int cur = ch & 1, nxt = cur ^ 1, c3 = ch % 3;
    if (w == 0) {
      // ---- serial engine, all in-register ----
      f32x16 a0, a1;
      #pragma unroll
      for (int i = 0; i < 16; ++i) { a0[i] = 0.f; a1[i] = 0.f; }
      #pragma unroll
      for (int kb = 0; kb < 8; kb += 2) {
        s16x8 ka = *(const s16x8*)(&Kh[cur][0] + lr * SK + 16 * kb + 8 * lh);
        s16x8 kbv = *(const s16x8*)(&Kh[cur][0] + lr * SK + 16 * (kb + 1) + 8 * lh);
        a0 = __builtin_amdgcn_mfma_f32_32x32x16_bf16(ka, Sfrag[kb], a0, 0, 0, 0);
        a1 = __builtin_amdgcn_mfma_f32_32x32x16_bf16(kbv, Sfrag[kb + 1], a1, 0, 0, 0);
      }
      f32x16 Wacc = a0 + a1;
      f32x16 Bv;
      #pragma unroll
      for (int i = 0; i < 16; ++i) {
        int row = rowmap(i, lh);
        float2 bb = ((const float2*)ls_bbf[cur])[row];
        Bv[i] = bb.x * vl[cur][row * VS + lr] - bb.y * Wacc[i];
      }
      u32 ub[8]; packq(Bv, ub);
      s16x8 bf0, bf1; swapfr(ub, bf0, bf1);
      f32x16 Uacc;
      #pragma unroll
      for (int i = 0; i < 16; ++i) Uacc[i] = 0.f;
      {
        s16x8 t0f = *(const s16x8*)(&Tl[cur][0] + lr * SG + 8 * lh);
        s16x8 t1f = *(const s16x8*)(&Tl[cur][0] + lr * SG + 16 + 8 * lh);
        Uacc = __builtin_amdgcn_mfma_f32_32x32x16_bf16(t0f, bf0, Uacc, 0, 0, 0);
        Uacc = __builtin_amdgcn_mfma_f32_32x32x16_bf16(t1f, bf1, Uacc, 0, 0, 0);
      }
      u32 uu[8]; packq(Uacc, uu);
      #pragma unroll
      for (int p = 0; p < 8; ++p)
        *(u32*)(&UT[cur][0] + lr * SRU + rowmap(2 * p, lh)) = uu[p];
      s16x8 uf0, uf1; swapfr(uu, uf0, uf1);
      const float ebL = ls_eb[c3][31];
      #pragma unroll
      for (int q = 0; q < 4; ++q) {
        f32x16 acc = Sst[q];
        s16x8 ka0 = ld8u(&KhT[cur][0] + (32 * q + lr) * SRT + 8 * lh);
        s16x8 ka1 = ld8u(&KhT[cur][0] + (32 * q + lr) * SRT + 16 + 8 * lh);
        acc = __builtin_amdgcn_mfma_f32_32x32x16_bf16(ka0, uf0, acc, 0, 0, 0);
        acc = __builtin_amdgcn_mfma_f32_32x32x16_bf16(ka1, uf1, acc, 0, 0, 0);
        #pragma unroll
        for (int i = 0; i < 16; ++i) Sst[q][i] = ebL * acc[i];
        u32 us[8]; packq(Sst[q], us);
        #pragma unroll
        for (int p = 0; p < 8; ++p)
          *(u32*)(&SbT[nxt][0] + lr * SK + 32 * q + rowmap(2 * p, lh)) = us[p];
        swapfr(us, Sfrag[2 * q], Sfrag[2 * q + 1]);
      }
    } else if (w == 1) {
      f32x16 Xn = mm8(&Qh[cur][0], &SbT[cur][0], lr, lh);
      if (ch > 0) {   // lagged O for chunk ch-1
        const int pc = (ch - 1) & 1, p3 = (ch - 1) % 3, tp = (ch - 1) * C;
        f32x16 Oacc = Xprev;
        #pragma unroll
        for (int kb = 0; kb < 2; ++kb) {
          s16x8 a = *(const s16x8*)(&Gl[p3][0] + lr * SG + 16 * kb + 8 * lh);
          s16x8 b = ld8u(&UT[pc][0] + lr * SRU + 16 * kb + 8 * lh);
          Oacc = __builtin_amdgcn_mfma_f32_32x32x16_bf16(a, b, Oacc, 0, 0, 0);
        }
        #pragma unroll
        for (int i = 0; i < 16; ++i) {
          const int row = rowmap(i, lh);
          oh[(size_t)(tp + row) * V_ + v0 + lr] = ls_eb[p3][row] * Oacc[i];
        }
      }
      Xprev = Xn;
    } else {
      if (ch + 1 < NCH) stage(nxt, (ch + 1) % 3);
      if (ch + 2 < NCH) prefetch(ch + 2);
    }
    bar_lds();
  }

  // epilogue: O for the last chunk
  if (w == 1) {
    const int pc = (NCH - 1) & 1, p3 = (NCH - 1) % 3, tp = (NCH - 1) * C;
    f32x16 Oacc = Xprev;
    #pragma unroll
    for (int kb = 0; kb < 2; ++kb) {
      s16x8 a = *(const s16x8*)(&Gl[p3][0] + lr * SG + 16 * kb + 8 * lh);
      s16x8 b = ld8u(&UT[pc][0] + lr * SRU + 16 * kb + 8 * lh);
      Oacc = __builtin_amdgcn_mfma_f32_32x32x16_bf16(a, b, Oacc, 0, 0, 0);
    }
    #pragma unroll
    for (int i = 0; i < 16; ++i) {
      const int row = rowmap(i, lh);
      oh[(size_t)(tp + row) * V_ + v0 + lr] = ls_eb[p3][row] * Oacc[i];
    }
  }
  // final state from w0 registers
  if (w == 0) {
    #pragma unroll
    for (int q = 0; q < 4; ++q) {
      float* sp = out + (size_t)BHn * T_ * V_
                      + ((size_t)bh * K_ + 32 * q) * V_ + v0 + lr;
      #pragma unroll
      for (int i = 0; i < 16; ++i)
        sp[(size_t)rowmap(i, lh) * V_] = Sst[q][i];
    }
  }
}

extern "C" void kernel_launch(void* const* d_in, const int* in_sizes, int n_in,
                              void* d_out, int out_size, void* d_ws, size_t ws_size,
                              hipStream_t stream) {
  const float* q    = (const float*)d_in[0];
  const float* k    = (const float*)d_in[1];
  const float* v    = (const float*)d_in[2];
  const float* g    = (const float*)d_in[3];
  const float* beta = (const float*)d_in[4];
  const float* s0   = (const float*)d_in[5];
  float* out = (float*)d_out;
  char* ws = (char*)d_ws;   // 64*64*4608 = 18.9 MB
  hipLaunchKernelGGL(gdn_pre_kernel, dim3(BHn * NCH), dim3(256), 0, stream,
                     q, k, g, beta, ws);
  hipLaunchKernelGGL(gdn_seq_kernel, dim3(BHn * NS), dim3(256), 0, stream,
                     q, k, v, s0, ws, out);
}

// Round 11
// 182.256 us; speedup vs baseline: 1.3141x; 1.1353x over previous
//
#include <hip/hip_runtime.h>
#include <math.h>

typedef float f32x16 __attribute__((ext_vector_type(16)));
typedef short s16x8 __attribute__((ext_vector_type(8)));
typedef unsigned int u32;

namespace {
constexpr int B_ = 4, H_ = 16, T_ = 2048, K_ = 128, V_ = 128;
constexpr int BHn = B_ * H_;
constexpr int C = 32;            // chunk length
constexpr int NCH = T_ / C;      // 64 chunks
constexpr int NS = 4;            // V slices (seq pass)
constexpr int VS = V_ / NS;      // 32 cols per block
constexpr float SCALE = 0.08838834764831845f; // 128^-0.5
constexpr int SK = 136;          // ushort stride, [*][128] arrays (16B-aligned rows)
constexpr int SRT = 36;          // ushort stride, KhT [128][32] (72B rows, 2-way-free)
constexpr int SRU = 36;          // ushort stride, UT [32][32]
constexpr int SG = 48;           // ushort stride, Tl/Gl tiles (96B rows)
constexpr int SF = 36;           // f32 stride, pre-pass Mm
constexpr size_t WSCH = 4608;    // ws/chunk: T 2048 | G 2048 | scal 512 (eb32,bbf64,niq32)
}

__device__ __forceinline__ ushort f2bf(float x) {
  unsigned u = __builtin_bit_cast(unsigned, x);
  u += 0x7FFF + ((u >> 16) & 1);       // RNE
  return (ushort)(u >> 16);
}
// packed bf16 pair via HW instruction (RNE): lo->bits0-15, hi->bits16-31
__device__ __forceinline__ u32 cvtpk(float lo, float hi) {
  u32 r;
  asm("v_cvt_pk_bf16_f32 %0, %1, %2" : "=v"(r) : "v"(lo), "v"(hi));
  return r;
}
__device__ __forceinline__ int rowmap(int i, int lh) { return (i & 3) + 8 * (i >> 2) + 4 * lh; }

// barrier waiting only on LDS ops: global loads/stores stay in flight
__device__ __forceinline__ void bar_lds() {
  asm volatile("s_waitcnt lgkmcnt(0)" ::: "memory");
  __builtin_amdgcn_s_barrier();
  asm volatile("" ::: "memory");
}

// 16B fragment from an 8B-aligned LDS row: two b64 loads
__device__ __forceinline__ s16x8 ld8u(const ushort* p) {
  uint2 a = *(const uint2*)(p);
  uint2 b = *(const uint2*)(p + 4);
  int4 r = make_int4((int)a.x, (int)a.y, (int)b.x, (int)b.y);
  return __builtin_bit_cast(s16x8, r);
}

// pack acc (C/D layout) into 8 bf16-pair u32s
__device__ __forceinline__ void packq(const f32x16& a, u32* u) {
  #pragma unroll
  for (int j = 0; j < 4; ++j) {
    u[2*j]   = cvtpk(a[4*j],   a[4*j+1]);
    u[2*j+1] = cvtpk(a[4*j+2], a[4*j+3]);
  }
}
// acc-layout packs -> MFMA b-operand fragments via v_permlane32_swap_b32
__device__ __forceinline__ void swapfr(const u32* u, s16x8& f0, s16x8& f1) {
  u32 a0 = u[0], b0 = u[2], a1 = u[1], b1 = u[3];
  u32 a2 = u[4], b2 = u[6], a3 = u[5], b3 = u[7];
  asm("v_permlane32_swap_b32 %0, %1" : "+v"(a0), "+v"(b0));
  asm("v_permlane32_swap_b32 %0, %1" : "+v"(a1), "+v"(b1));
  asm("v_permlane32_swap_b32 %0, %1" : "+v"(a2), "+v"(b2));
  asm("v_permlane32_swap_b32 %0, %1" : "+v"(a3), "+v"(b3));
  f0 = __builtin_bit_cast(s16x8, make_int4((int)a0, (int)a1, (int)b0, (int)b1));
  f1 = __builtin_bit_cast(s16x8, make_int4((int)a2, (int)a3, (int)b2, (int)b3));
}

// full-K (128) tile matmul from LDS: A * Barr^T, both stride SK
__device__ __forceinline__ f32x16 mm8(const ushort* A, const ushort* B, int lr, int lh) {
  f32x16 a0, a1;
  #pragma unroll
  for (int i = 0; i < 16; ++i) { a0[i] = 0.f; a1[i] = 0.f; }
  #pragma unroll
  for (int kb = 0; kb < 8; kb += 2) {
    const int o0 = lr * SK + 16 * kb + 8 * lh, o1 = o0 + 16;
    a0 = __builtin_amdgcn_mfma_f32_32x32x16_bf16(*(const s16x8*)(A + o0),
                                                 *(const s16x8*)(B + o0), a0, 0, 0, 0);
    a1 = __builtin_amdgcn_mfma_f32_32x32x16_bf16(*(const s16x8*)(A + o1),
                                                 *(const s16x8*)(B + o1), a1, 0, 0, 0);
  }
  return a0 + a1;
}

// ============ pass 1: chunk-local precompute (4096 independent blocks) ============
__global__ __launch_bounds__(256, 2)
void gdn_pre_kernel(const float* __restrict__ qg, const float* __restrict__ kg,
                    const float* __restrict__ gg, const float* __restrict__ bg,
                    char* __restrict__ ws)
{
  const int bid = blockIdx.x;
  const int bh = bid >> 6, ch = bid & 63;
  const int t = threadIdx.x, w = t >> 6, l = t & 63, lr = l & 31, lh = l >> 5;
  const int r8 = t >> 3, c8 = t & 7;
  const int t0 = ch * C;

  __shared__ __align__(16) ushort Kh[C * SK], Qh[C * SK];
  __shared__ __align__(16) float Mm[C * SF];
  __shared__ __align__(16) ushort Tt[C * 32], Gt[C * 32];
  __shared__ float ls_g[C], ls_b[C], ls_eb[C], ls_emb[C], ls_nq[C];

  { // stage + normalize q,k
    const float4* q4 = (const float4*)(qg + ((size_t)bh * T_ + t0 + r8) * K_);
    const float4* k4 = (const float4*)(kg + ((size_t)bh * T_ + t0 + r8) * K_);
    float4 qv[4], kv[4]; float sq = 0.f, sk = 0.f;
    #pragma unroll
    for (int c = 0; c < 4; ++c) {
      qv[c] = q4[c8 + 8 * c]; kv[c] = k4[c8 + 8 * c];
      sq += qv[c].x*qv[c].x + qv[c].y*qv[c].y + qv[c].z*qv[c].z + qv[c].w*qv[c].w;
      sk += kv[c].x*kv[c].x + kv[c].y*kv[c].y + kv[c].z*kv[c].z + kv[c].w*kv[c].w;
    }
    sq += __shfl_xor(sq, 1); sq += __shfl_xor(sq, 2); sq += __shfl_xor(sq, 4);
    sk += __shfl_xor(sk, 1); sk += __shfl_xor(sk, 2); sk += __shfl_xor(sk, 4);
    const float niq = SCALE / fmaxf(sqrtf(sq), 1e-12f);
    const float nik = 1.0f / fmaxf(sqrtf(sk), 1e-12f);
    if (c8 == 0) ls_nq[r8] = niq;
    #pragma unroll
    for (int c = 0; c < 4; ++c) {
      const int f4 = c8 + 8 * c;
      uint2 upk, upq;
      upk.x = cvtpk(kv[c].x * nik, kv[c].y * nik);
      upk.y = cvtpk(kv[c].z * nik, kv[c].w * nik);
      upq.x = cvtpk(qv[c].x * niq, qv[c].y * niq);
      upq.y = cvtpk(qv[c].z * niq, qv[c].w * niq);
      *(uint2*)(Kh + r8 * SK + f4 * 4) = upk;
      *(uint2*)(Qh + r8 * SK + f4 * 4) = upq;
    }
    if (t < C)          ls_g[t]     = gg[(size_t)bh * T_ + t0 + t];
    else if (t < 2 * C) ls_b[t - C] = bg[(size_t)bh * T_ + t0 + t - C];
  }
  __syncthreads();
  if (w == 3 && l < 32) {   // inclusive prefix of g
    float x = ls_g[l];
    #pragma unroll
    for (int d = 1; d < 32; d <<= 1) { float y = __shfl_up(x, d); if (l >= d) x += y; }
    ls_eb[l] = expf(x); ls_emb[l] = expf(-x);
  }
  if (w == 0) {
    f32x16 acc = mm8(Kh, Kh, lr, lh);
    #pragma unroll
    for (int i = 0; i < 16; ++i) Mm[rowmap(i, lh) * SF + lr] = acc[i];
  }
  if (w == 1) {
    f32x16 acc = mm8(Qh, Kh, lr, lh);
    #pragma unroll
    for (int i = 0; i < 16; ++i) {
      int row = rowmap(i, lh);
      Gt[row * 32 + lr] = (lr <= row) ? f2bf(acc[i]) : (ushort)0;
    }
  }
  __syncthreads();
  if (w == 2 && l < 32) {   // T = (I + tril_strict(diag(b) M))^-1, column l
    const int j = l;
    float x[32];
    #pragma unroll
    for (int m = 0; m < 32; ++m) x[m] = (m == j) ? 1.f : 0.f;
    #pragma unroll
    for (int r = 1; r < 32; ++r) {
      const float* mr = Mm + r * SF;
      float p0 = 0.f, p1 = 0.f, p2 = 0.f, p3 = 0.f;
      #pragma unroll
      for (int jb = 0; jb + 4 <= r; jb += 4) {
        float4 m4 = *(const float4*)(mr + jb);
        p0 = fmaf(m4.x, x[jb + 0], p0);
        p1 = fmaf(m4.y, x[jb + 1], p1);
        p2 = fmaf(m4.z, x[jb + 2], p2);
        p3 = fmaf(m4.w, x[jb + 3], p3);
      }
      #pragma unroll
      for (int m = (r & ~3); m < r; ++m) p1 = fmaf(mr[m], x[m], p1);
      float xr = -ls_b[r] * ((p0 + p1) + (p2 + p3));
      if (r > j) x[r] = xr;
    }
    #pragma unroll
    for (int r = 0; r < 32; ++r) Tt[r * 32 + j] = f2bf(x[r]);
  }
  __syncthreads();
  { // copy to ws  (scal: eb[32] | (bev,bet)[64] | niq[32])
    char* wsb = ws + ((size_t)bh * NCH + ch) * WSCH;
    u32* wT = (u32*)wsb; u32* wG = (u32*)(wsb + 2048); float* wS = (float*)(wsb + 4096);
    const u32* sT = (const u32*)Tt; const u32* sG = (const u32*)Gt;
    wT[t] = sT[t]; wT[t + 256] = sT[t + 256];
    wG[t] = sG[t]; wG[t + 256] = sG[t + 256];
    if (t < 32)      wS[t] = ls_eb[t];
    else if (t < 96) {
      int j = t - 32, r = j >> 1;
      wS[t] = (j & 1) ? ls_b[r] : ls_b[r] * ls_emb[r];
    } else if (t < 128) wS[t] = ls_nq[t - 96];
  }
}

// ============ pass 2: sequential scan (256 blocks, 1 barrier/chunk) ============
__global__ __launch_bounds__(256, 1)
void gdn_seq_kernel(const float* __restrict__ qg, const float* __restrict__ kg,
                    const float* __restrict__ vg, const float* __restrict__ s0,
                    const char* __restrict__ ws, float* __restrict__ out)
{
  const int bid = blockIdx.x;
  const int xcd = bid & 7, qd = bid >> 3;
  const int bh = (qd >> 2) * 8 + xcd;
  const int v0 = (qd & 3) * VS;
  const int t = threadIdx.x, w = t >> 6, l = t & 63, lr = l & 31, lh = l >> 5;
  const int ts = t & 127;               // stager index (w>=2)
  const int r4 = ts >> 2, c4 = ts & 3;

  __shared__ __align__(16) ushort Kh[2][C * SK];
  __shared__ __align__(16) ushort KhT[2][K_ * SRT];
  __shared__ __align__(16) ushort Tl[2][C * SG], Gl[3][C * SG];
  __shared__ __align__(16) float  vl[2][C * VS];
  __shared__ __align__(16) float  ls_eb[3][C];
  __shared__ __align__(16) float  ls_bbf[2][2 * C];   // interleaved (bev,bet)
  __shared__ __align__(16) ushort UT[2][32 * SRU];
  __shared__ __align__(16) ushort SbT[2][32 * SK];    // bf16 S^T [v][k], dbuf

  const float* qh = qg + (size_t)bh * T_ * K_;
  const float* kh = kg + (size_t)bh * T_ * K_;
  const float* vh = vg + (size_t)bh * T_ * V_;
  const char* wsh = ws + (size_t)bh * NCH * WSCH;
  float* oh = out + (size_t)bh * T_ * V_;

  // ---- w0: full state in registers (4 quadrants x f32x16) ----
  f32x16 Sst[4];
  s16x8 Sfrag[8];            // bf16 S^T b-operand fragments
  if (w == 0) {
    #pragma unroll
    for (int q = 0; q < 4; ++q) {
      const float* sp = s0 + ((size_t)bh * K_ + 32 * q) * V_ + v0 + lr;
      #pragma unroll
      for (int i = 0; i < 16; i += 2) {
        int row = rowmap(i, lh);
        Sst[q][i]     = sp[(size_t)row * V_];
        Sst[q][i + 1] = sp[(size_t)(row + 1) * V_];
      }
      u32 us[8]; packq(Sst[q], us);
      #pragma unroll
      for (int p = 0; p < 8; ++p)
        *(u32*)(&SbT[0][0] + lr * SK + 32 * q + rowmap(2 * p, lh)) = us[p];
      swapfr(us, Sfrag[2 * q], Sfrag[2 * q + 1]);
    }
  }

  // ---- w1: q prefetch registers (global-q X path) ----
  float4 pq4[16]; float pniq = 0.f;
  auto qprefetch = [&](int cc) {
    const float4* q4 = (const float4*)(qh + (size_t)(cc * C + lr) * K_);
    #pragma unroll
    for (int kb = 0; kb < 8; ++kb) {
      pq4[2 * kb]     = q4[4 * kb + 2 * lh];
      pq4[2 * kb + 1] = q4[4 * kb + 2 * lh + 1];
    }
    pniq = ((const float*)(wsh + (size_t)cc * WSCH + 4096))[96 + lr];
  };

  // ---- stagers (w2/w3): k, v, T, G, scalars ----
  float4 pk[8], pv[2];
  u32 pT[4], pG[4]; float psc = 0.f;
  auto prefetch = [&](int cc) {
    const float4* k4 = (const float4*)(kh + (size_t)(cc * C + r4) * K_);
    #pragma unroll
    for (int j = 0; j < 8; ++j) pk[j] = k4[c4 + 4 * j];
    const float4* v4 = (const float4*)(vh + (size_t)(cc * C + r4) * V_ + v0);
    pv[0] = v4[c4]; pv[1] = v4[c4 + 4];
    const char* wsb = wsh + (size_t)cc * WSCH;
    #pragma unroll
    for (int j = 0; j < 4; ++j) {
      pT[j] = ((const u32*)wsb)[ts + 128 * j];
      pG[j] = ((const u32*)(wsb + 2048))[ts + 128 * j];
    }
    psc = (ts < 96) ? ((const float*)(wsb + 4096))[ts] : 0.f;
  };
  auto stage = [&](int b, int b3) {
    float sk = 0.f;
    #pragma unroll
    for (int j = 0; j < 8; ++j)
      sk += pk[j].x*pk[j].x + pk[j].y*pk[j].y + pk[j].z*pk[j].z + pk[j].w*pk[j].w;
    sk += __shfl_xor(sk, 1); sk += __shfl_xor(sk, 2);
    const float nik = 1.0f / fmaxf(sqrtf(sk), 1e-12f);
    #pragma unroll
    for (int j = 0; j < 8; ++j) {
      const int f4 = c4 + 4 * j;
      uint2 upk;
      upk.x = cvtpk(pk[j].x * nik, pk[j].y * nik);
      upk.y = cvtpk(pk[j].z * nik, pk[j].w * nik);
      *(uint2*)(&Kh[b][0] + r4 * SK + 4 * f4) = upk;
      ushort* kt = &KhT[b][0] + (4 * f4) * SRT + r4;
      kt[0]       = (ushort)upk.x;
      kt[SRT]     = (ushort)(upk.x >> 16);
      kt[2 * SRT] = (ushort)upk.y;
      kt[3 * SRT] = (ushort)(upk.y >> 16);
    }
    *(float4*)(&vl[b][0] + r4 * VS + 4 * c4) = pv[0];
    *(float4*)(&vl[b][0] + r4 * VS + 4 * (c4 + 4)) = pv[1];
    #pragma unroll
    for (int j = 0; j < 4; ++j) {
      int e = ts + 128 * j;
      *(u32*)(&Tl[b][0]  + (e >> 4) * SG + 2 * (e & 15)) = pT[j];
      *(u32*)(&Gl[b3][0] + (e >> 4) * SG + 2 * (e & 15)) = pG[j];
    }
    if (ts < 32)      ls_eb[b3][ts]      = psc;
    else if (ts < 96) ls_bbf[b][ts - 32] = psc;
  };

  if (w >= 2)      { prefetch(0); stage(0, 0); prefetch(1); }
  else if (w == 1) { qprefetch(0); }
  bar_lds();

  f32x16 Xprev;
  for (int ch = 0; ch < NCH; ++ch) {
    const int cur = ch & 1, nxt = cur ^ 1, c3 = ch % 3;
    if (w == 0) {
      // ---- serial engine, all in-register ----
      f32x16 a0, a1;
      #pragma unroll
      for (int i = 0; i < 16; ++i) { a0[i] = 0.f; a1[i] = 0.f; }
      #pragma unroll
      for (int kb = 0; kb < 8; kb += 2) {
        s16x8 ka = *(const s16x8*)(&Kh[cur][0] + lr * SK + 16 * kb + 8 * lh);
        s16x8 kbv = *(const s16x8*)(&Kh[cur][0] + lr * SK + 16 * (kb + 1) + 8 * lh);
        a0 = __builtin_amdgcn_mfma_f32_32x32x16_bf16(ka, Sfrag[kb], a0, 0, 0, 0);
        a1 = __builtin_amdgcn_mfma_f32_32x32x16_bf16(kbv, Sfrag[kb + 1], a1, 0, 0, 0);
      }
      f32x16 Wacc = a0 + a1;
      f32x16 Bv;
      #pragma unroll
      for (int i = 0; i < 16; ++i) {
        int row = rowmap(i, lh);
        float2 bb = ((const float2*)ls_bbf[cur])[row];
        Bv[i] = bb.x * vl[cur][row * VS + lr] - bb.y * Wacc[i];
      }
      u32 ub[8]; packq(Bv, ub);
      s16x8 bf0, bf1; swapfr(ub, bf0, bf1);
      f32x16 Uacc;
      #pragma unroll
      for (int i = 0; i < 16; ++i) Uacc[i] = 0.f;
      {
        s16x8 t0f = *(const s16x8*)(&Tl[cur][0] + lr * SG + 8 * lh);
        s16x8 t1f = *(const s16x8*)(&Tl[cur][0] + lr * SG + 16 + 8 * lh);
        Uacc = __builtin_amdgcn_mfma_f32_32x32x16_bf16(t0f, bf0, Uacc, 0, 0, 0);
        Uacc = __builtin_amdgcn_mfma_f32_32x32x16_bf16(t1f, bf1, Uacc, 0, 0, 0);
      }
      u32 uu[8]; packq(Uacc, uu);
      #pragma unroll
      for (int p = 0; p < 8; ++p)
        *(u32*)(&UT[cur][0] + lr * SRU + rowmap(2 * p, lh)) = uu[p];
      s16x8 uf0, uf1; swapfr(uu, uf0, uf1);
      const float ebL = ls_eb[c3][31];
      #pragma unroll
      for (int q = 0; q < 4; ++q) {
        f32x16 acc = Sst[q];
        s16x8 ka0 = ld8u(&KhT[cur][0] + (32 * q + lr) * SRT + 8 * lh);
        s16x8 ka1 = ld8u(&KhT[cur][0] + (32 * q + lr) * SRT + 16 + 8 * lh);
        acc = __builtin_amdgcn_mfma_f32_32x32x16_bf16(ka0, uf0, acc, 0, 0, 0);
        acc = __builtin_amdgcn_mfma_f32_32x32x16_bf16(ka1, uf1, acc, 0, 0, 0);
        #pragma unroll
        for (int i = 0; i < 16; ++i) Sst[q][i] = ebL * acc[i];
        u32 us[8]; packq(Sst[q], us);
        #pragma unroll
        for (int p = 0; p < 8; ++p)
          *(u32*)(&SbT[nxt][0] + lr * SK + 32 * q + rowmap(2 * p, lh)) = us[p];
        swapfr(us, Sfrag[2 * q], Sfrag[2 * q + 1]);
      }
    } else if (w == 1) {
      // X = Qhat.S from global-q fragments (pq4 holds chunk ch)
      f32x16 x0, x1;
      #pragma unroll
      for (int i = 0; i < 16; ++i) { x0[i] = 0.f; x1[i] = 0.f; }
      #pragma unroll
      for (int kb = 0; kb < 8; kb += 2) {
        u32 qa0 = cvtpk(pq4[2*kb].x * pniq,   pq4[2*kb].y * pniq);
        u32 qa1 = cvtpk(pq4[2*kb].z * pniq,   pq4[2*kb].w * pniq);
        u32 qa2 = cvtpk(pq4[2*kb+1].x * pniq, pq4[2*kb+1].y * pniq);
        u32 qa3 = cvtpk(pq4[2*kb+1].z * pniq, pq4[2*kb+1].w * pniq);
        s16x8 qa = __builtin_bit_cast(s16x8, make_int4((int)qa0,(int)qa1,(int)qa2,(int)qa3));
        u32 qb0 = cvtpk(pq4[2*kb+2].x * pniq, pq4[2*kb+2].y * pniq);
        u32 qb1 = cvtpk(pq4[2*kb+2].z * pniq, pq4[2*kb+2].w * pniq);
        u32 qb2 = cvtpk(pq4[2*kb+3].x * pniq, pq4[2*kb+3].y * pniq);
        u32 qb3 = cvtpk(pq4[2*kb+3].z * pniq, pq4[2*kb+3].w * pniq);
        s16x8 qb = __builtin_bit_cast(s16x8, make_int4((int)qb0,(int)qb1,(int)qb2,(int)qb3));
        x0 = __builtin_amdgcn_mfma_f32_32x32x16_bf16(
                 qa, *(const s16x8*)(&SbT[cur][0] + lr * SK + 16 * kb + 8 * lh), x0, 0, 0, 0);
        x1 = __builtin_amdgcn_mfma_f32_32x32x16_bf16(
                 qb, *(const s16x8*)(&SbT[cur][0] + lr * SK + 16 * (kb + 1) + 8 * lh), x1, 0, 0, 0);
      }
      f32x16 Xn = x0 + x1;
      if (ch > 0) {   // lagged O for chunk ch-1
        const int pc = (ch - 1) & 1, p3 = (ch - 1) % 3, tp = (ch - 1) * C;
        f32x16 Oacc = Xprev;
        #pragma unroll
        for (int kb = 0; kb < 2; ++kb) {
          s16x8 a = *(const s16x8*)(&Gl[p3][0] + lr * SG + 16 * kb + 8 * lh);
          s16x8 b = ld8u(&UT[pc][0] + lr * SRU + 16 * kb + 8 * lh);
          Oacc = __builtin_amdgcn_mfma_f32_32x32x16_bf16(a, b, Oacc, 0, 0, 0);
        }
        #pragma unroll
        for (int i = 0; i < 16; ++i) {
          const int row = rowmap(i, lh);
          oh[(size_t)(tp + row) * V_ + v0 + lr] = ls_eb[p3][row] * Oacc[i];
        }
      }
      Xprev = Xn;
      if (ch + 1 < NCH) qprefetch(ch + 1);
    } else {
      if (ch + 1 < NCH) stage(nxt, (ch + 1) % 3);
      if (ch + 2 < NCH) prefetch(ch + 2);
    }
    bar_lds();
  }

  // epilogue: O for the last chunk
  if (w == 1) {
    const int pc = (NCH - 1) & 1, p3 = (NCH - 1) % 3, tp = (NCH - 1) * C;
    f32x16 Oacc = Xprev;
    #pragma unroll
    for (int kb = 0; kb < 2; ++kb) {
      s16x8 a = *(const s16x8*)(&Gl[p3][0] + lr * SG + 16 * kb + 8 * lh);
      s16x8 b = ld8u(&UT[pc][0] + lr * SRU + 16 * kb + 8 * lh);
      Oacc = __builtin_amdgcn_mfma_f32_32x32x16_bf16(a, b, Oacc, 0, 0, 0);
    }
    #pragma unroll
    for (int i = 0; i < 16; ++i) {
      const int row = rowmap(i, lh);
      oh[(size_t)(tp + row) * V_ + v0 + lr] = ls_eb[p3][row] * Oacc[i];
    }
  }
  // final state from w0 registers
  if (w == 0) {
    #pragma unroll
    for (int q = 0; q < 4; ++q) {
      float* sp = out + (size_t)BHn * T_ * V_
                      + ((size_t)bh * K_ + 32 * q) * V_ + v0 + lr;
      #pragma unroll
      for (int i = 0; i < 16; ++i)
        sp[(size_t)rowmap(i, lh) * V_] = Sst[q][i];
    }
  }
}

extern "C" void kernel_launch(void* const* d_in, const int* in_sizes, int n_in,
                              void* d_out, int out_size, void* d_ws, size_t ws_size,
                              hipStream_t stream) {
  const float* q    = (const float*)d_in[0];
  const float* k    = (const float*)d_in[1];
  const float* v    = (const float*)d_in[2];
  const float* g    = (const float*)d_in[3];
  const float* beta = (const float*)d_in[4];
  const float* s0   = (const float*)d_in[5];
  float* out = (float*)d_out;
  char* ws = (char*)d_ws;   // 64*64*4608 = 18.9 MB
  hipLaunchKernelGGL(gdn_pre_kernel, dim3(BHn * NCH), dim3(256), 0, stream,
                     q, k, g, beta, ws);
  hipLaunchKernelGGL(gdn_seq_kernel, dim3(BHn * NS), dim3(256), 0, stream,
                     q, k, v, s0, ws, out);
}

// Round 12
// 154.498 us; speedup vs baseline: 1.5502x; 1.1797x over previous
//
#include <hip/hip_runtime.h>
#include <math.h>

typedef float f32x16 __attribute__((ext_vector_type(16)));
typedef short s16x8 __attribute__((ext_vector_type(8)));
typedef unsigned int u32;

namespace {
constexpr int B_ = 4, H_ = 16, T_ = 2048, K_ = 128, V_ = 128;
constexpr int BHn = B_ * H_;
constexpr int C = 32;            // chunk length
constexpr int NCH = T_ / C;      // 64 chunks
constexpr int NS = 4;            // V slices (seq pass)
constexpr int VS = V_ / NS;      // 32 cols per block
constexpr float SCALE = 0.08838834764831845f; // 128^-0.5
constexpr int SK = 136;          // ushort stride, [*][128] arrays (16B-aligned rows)
constexpr int SRT = 36;          // ushort stride, KhT [128][32] (72B rows, 2-way-free)
constexpr int SRU = 36;          // ushort stride, UT [32][32]
constexpr int SF = 36;           // f32 stride, pre-pass Mm
constexpr size_t WSCH = 4608;    // ws/chunk: T 2048 | G 2048 | scal 512 (eb32,bbf64,niq32)
}

__device__ __forceinline__ ushort f2bf(float x) {
  unsigned u = __builtin_bit_cast(unsigned, x);
  u += 0x7FFF + ((u >> 16) & 1);       // RNE
  return (ushort)(u >> 16);
}
// packed bf16 pair via HW instruction (RNE): lo->bits0-15, hi->bits16-31
__device__ __forceinline__ u32 cvtpk(float lo, float hi) {
  u32 r;
  asm("v_cvt_pk_bf16_f32 %0, %1, %2" : "=v"(r) : "v"(lo), "v"(hi));
  return r;
}
__device__ __forceinline__ int rowmap(int i, int lh) { return (i & 3) + 8 * (i >> 2) + 4 * lh; }

// barrier waiting only on LDS ops: global loads/stores stay in flight
__device__ __forceinline__ void bar_lds() {
  asm volatile("s_waitcnt lgkmcnt(0)" ::: "memory");
  __builtin_amdgcn_s_barrier();
  asm volatile("" ::: "memory");
}

// 16B fragment from an 8B-aligned LDS row: two b64 loads
__device__ __forceinline__ s16x8 ld8u(const ushort* p) {
  uint2 a = *(const uint2*)(p);
  uint2 b = *(const uint2*)(p + 4);
  int4 r = make_int4((int)a.x, (int)a.y, (int)b.x, (int)b.y);
  return __builtin_bit_cast(s16x8, r);
}

// pack acc (C/D layout) into 8 bf16-pair u32s
__device__ __forceinline__ void packq(const f32x16& a, u32* u) {
  #pragma unroll
  for (int j = 0; j < 4; ++j) {
    u[2*j]   = cvtpk(a[4*j],   a[4*j+1]);
    u[2*j+1] = cvtpk(a[4*j+2], a[4*j+3]);
  }
}
// acc-layout packs -> MFMA b-operand fragments via v_permlane32_swap_b32
__device__ __forceinline__ void swapfr(const u32* u, s16x8& f0, s16x8& f1) {
  u32 a0 = u[0], b0 = u[2], a1 = u[1], b1 = u[3];
  u32 a2 = u[4], b2 = u[6], a3 = u[5], b3 = u[7];
  asm("v_permlane32_swap_b32 %0, %1" : "+v"(a0), "+v"(b0));
  asm("v_permlane32_swap_b32 %0, %1" : "+v"(a1), "+v"(b1));
  asm("v_permlane32_swap_b32 %0, %1" : "+v"(a2), "+v"(b2));
  asm("v_permlane32_swap_b32 %0, %1" : "+v"(a3), "+v"(b3));
  f0 = __builtin_bit_cast(s16x8, make_int4((int)a0, (int)a1, (int)b0, (int)b1));
  f1 = __builtin_bit_cast(s16x8, make_int4((int)a2, (int)a3, (int)b2, (int)b3));
}

// full-K (128) tile matmul from LDS: A * Barr^T, both stride SK
__device__ __forceinline__ f32x16 mm8(const ushort* A, const ushort* B, int lr, int lh) {
  f32x16 a0, a1;
  #pragma unroll
  for (int i = 0; i < 16; ++i) { a0[i] = 0.f; a1[i] = 0.f; }
  #pragma unroll
  for (int kb = 0; kb < 8; kb += 2) {
    const int o0 = lr * SK + 16 * kb + 8 * lh, o1 = o0 + 16;
    a0 = __builtin_amdgcn_mfma_f32_32x32x16_bf16(*(const s16x8*)(A + o0),
                                                 *(const s16x8*)(B + o0), a0, 0, 0, 0);
    a1 = __builtin_amdgcn_mfma_f32_32x32x16_bf16(*(const s16x8*)(A + o1),
                                                 *(const s16x8*)(B + o1), a1, 0, 0, 0);
  }
  return a0 + a1;
}

// ============ pass 1: chunk-local precompute (4096 independent blocks) ============
__global__ __launch_bounds__(256, 3)
void gdn_pre_kernel(const float* __restrict__ qg, const float* __restrict__ kg,
                    const float* __restrict__ gg, const float* __restrict__ bg,
                    char* __restrict__ ws)
{
  const int bid = blockIdx.x;
  const int bh = bid >> 6, ch = bid & 63;
  const int t = threadIdx.x, w = t >> 6, l = t & 63, lr = l & 31, lh = l >> 5;
  const int r8 = t >> 3, c8 = t & 7;
  const int t0 = ch * C;

  __shared__ __align__(16) ushort Kh[C * SK], Qh[C * SK];
  __shared__ __align__(16) float Mm[C * SF];
  __shared__ __align__(16) ushort Tt[C * 32], Gt[C * 32];
  __shared__ float ls_g[C], ls_b[C], ls_eb[C], ls_emb[C], ls_nq[C];

  { // stage + normalize q,k
    const float4* q4 = (const float4*)(qg + ((size_t)bh * T_ + t0 + r8) * K_);
    const float4* k4 = (const float4*)(kg + ((size_t)bh * T_ + t0 + r8) * K_);
    float4 qv[4], kv[4]; float sq = 0.f, sk = 0.f;
    #pragma unroll
    for (int c = 0; c < 4; ++c) {
      qv[c] = q4[c8 + 8 * c]; kv[c] = k4[c8 + 8 * c];
      sq += qv[c].x*qv[c].x + qv[c].y*qv[c].y + qv[c].z*qv[c].z + qv[c].w*qv[c].w;
      sk += kv[c].x*kv[c].x + kv[c].y*kv[c].y + kv[c].z*kv[c].z + kv[c].w*kv[c].w;
    }
    sq += __shfl_xor(sq, 1); sq += __shfl_xor(sq, 2); sq += __shfl_xor(sq, 4);
    sk += __shfl_xor(sk, 1); sk += __shfl_xor(sk, 2); sk += __shfl_xor(sk, 4);
    const float niq = SCALE / fmaxf(sqrtf(sq), 1e-12f);
    const float nik = 1.0f / fmaxf(sqrtf(sk), 1e-12f);
    if (c8 == 0) ls_nq[r8] = niq;
    #pragma unroll
    for (int c = 0; c < 4; ++c) {
      const int f4 = c8 + 8 * c;
      uint2 upk, upq;
      upk.x = cvtpk(kv[c].x * nik, kv[c].y * nik);
      upk.y = cvtpk(kv[c].z * nik, kv[c].w * nik);
      upq.x = cvtpk(qv[c].x * niq, qv[c].y * niq);
      upq.y = cvtpk(qv[c].z * niq, qv[c].w * niq);
      *(uint2*)(Kh + r8 * SK + f4 * 4) = upk;
      *(uint2*)(Qh + r8 * SK + f4 * 4) = upq;
    }
    if (t < C)          ls_g[t]     = gg[(size_t)bh * T_ + t0 + t];
    else if (t < 2 * C) ls_b[t - C] = bg[(size_t)bh * T_ + t0 + t - C];
  }
  __syncthreads();
  if (w == 3 && l < 32) {   // inclusive prefix of g
    float x = ls_g[l];
    #pragma unroll
    for (int d = 1; d < 32; d <<= 1) { float y = __shfl_up(x, d); if (l >= d) x += y; }
    ls_eb[l] = expf(x); ls_emb[l] = expf(-x);
  }
  if (w == 0) {
    f32x16 acc = mm8(Kh, Kh, lr, lh);
    #pragma unroll
    for (int i = 0; i < 16; ++i) Mm[rowmap(i, lh) * SF + lr] = acc[i];
  }
  if (w == 1) {
    f32x16 acc = mm8(Qh, Kh, lr, lh);
    #pragma unroll
    for (int i = 0; i < 16; ++i) {
      int row = rowmap(i, lh);
      Gt[row * 32 + lr] = (lr <= row) ? f2bf(acc[i]) : (ushort)0;
    }
  }
  __syncthreads();
  if (w == 2 && l < 32) {   // T = (I + tril_strict(diag(b) M))^-1, column l
    const int j = l;
    float x[32];
    #pragma unroll
    for (int m = 0; m < 32; ++m) x[m] = (m == j) ? 1.f : 0.f;
    #pragma unroll
    for (int r = 1; r < 32; ++r) {
      const float* mr = Mm + r * SF;
      float p0 = 0.f, p1 = 0.f, p2 = 0.f, p3 = 0.f;
      #pragma unroll
      for (int jb = 0; jb + 4 <= r; jb += 4) {
        float4 m4 = *(const float4*)(mr + jb);
        p0 = fmaf(m4.x, x[jb + 0], p0);
        p1 = fmaf(m4.y, x[jb + 1], p1);
        p2 = fmaf(m4.z, x[jb + 2], p2);
        p3 = fmaf(m4.w, x[jb + 3], p3);
      }
      #pragma unroll
      for (int m = (r & ~3); m < r; ++m) p1 = fmaf(mr[m], x[m], p1);
      float xr = -ls_b[r] * ((p0 + p1) + (p2 + p3));
      if (r > j) x[r] = xr;
    }
    #pragma unroll
    for (int r = 0; r < 32; ++r) Tt[r * 32 + j] = f2bf(x[r]);
  }
  __syncthreads();
  { // copy to ws  (scal: eb[32] | (bev,bet)[64] | niq[32])
    char* wsb = ws + ((size_t)bh * NCH + ch) * WSCH;
    u32* wT = (u32*)wsb; u32* wG = (u32*)(wsb + 2048); float* wS = (float*)(wsb + 4096);
    const u32* sT = (const u32*)Tt; const u32* sG = (const u32*)Gt;
    wT[t] = sT[t]; wT[t + 256] = sT[t + 256];
    wG[t] = sG[t]; wG[t + 256] = sG[t + 256];
    if (t < 32)      wS[t] = ls_eb[t];
    else if (t < 96) {
      int j = t - 32, r = j >> 1;
      wS[t] = (j & 1) ? ls_b[r] : ls_b[r] * ls_emb[r];
    } else if (t < 128) wS[t] = ls_nq[t - 96];
  }
}

// ============ pass 2: sequential scan (256 blocks, 1 barrier/chunk) ============
__global__ __launch_bounds__(256, 1)
void gdn_seq_kernel(const float* __restrict__ qg, const float* __restrict__ kg,
                    const float* __restrict__ vg, const float* __restrict__ s0,
                    const char* __restrict__ ws, float* __restrict__ out)
{
  const int bid = blockIdx.x;
  const int xcd = bid & 7, qd = bid >> 3;
  const int bh = (qd >> 2) * 8 + xcd;
  const int v0 = (qd & 3) * VS;
  const int t = threadIdx.x, w = t >> 6, l = t & 63, lr = l & 31, lh = l >> 5;
  const int ts = t & 127;               // stager index (w>=2)
  const int r4 = ts >> 2, c4 = ts & 3;

  __shared__ __align__(16) ushort Kh[2][C * SK];
  __shared__ __align__(16) ushort KhT[2][K_ * SRT];
  __shared__ __align__(16) float  ls_eb[3][C];
  __shared__ __align__(16) float  ls_bbf[2][2 * C];   // interleaved (bev,bet)
  __shared__ __align__(16) ushort UT[2][32 * SRU];
  __shared__ __align__(16) ushort SbT[2][32 * SK];    // bf16 S^T [v][k], dbuf

  const float* qh = qg + (size_t)bh * T_ * K_;
  const float* kh = kg + (size_t)bh * T_ * K_;
  const float* vh = vg + (size_t)bh * T_ * V_;
  const char* wsh = ws + (size_t)bh * NCH * WSCH;
  float* oh = out + (size_t)bh * T_ * V_;

  // ---- w0: full state in registers (4 quadrants x f32x16) ----
  f32x16 Sst[4];
  s16x8 Sfrag[8];            // bf16 S^T b-operand fragments
  float pvvA[16], pvvB[16];  // w0 v prefetch (double-buffer, static)
  s16x8 pTfA[2], pTfB[2];    // w0 T-fragment prefetch
  if (w == 0) {
    #pragma unroll
    for (int q = 0; q < 4; ++q) {
      const float* sp = s0 + ((size_t)bh * K_ + 32 * q) * V_ + v0 + lr;
      #pragma unroll
      for (int i = 0; i < 16; i += 2) {
        int row = rowmap(i, lh);
        Sst[q][i]     = sp[(size_t)row * V_];
        Sst[q][i + 1] = sp[(size_t)(row + 1) * V_];
      }
      u32 us[8]; packq(Sst[q], us);
      #pragma unroll
      for (int p = 0; p < 8; ++p)
        *(u32*)(&SbT[0][0] + lr * SK + 32 * q + rowmap(2 * p, lh)) = us[p];
      swapfr(us, Sfrag[2 * q], Sfrag[2 * q + 1]);
    }
    { // prologue: v/T for chunk 0
      const float* vb = vh + (size_t)v0 + lr;
      #pragma unroll
      for (int i = 0; i < 16; ++i) pvvA[i] = vb[(size_t)rowmap(i, lh) * V_];
      const ushort* Tg = (const ushort*)wsh;
      pTfA[0] = *(const s16x8*)(Tg + lr * 32 + 8 * lh);
      pTfA[1] = *(const s16x8*)(Tg + lr * 32 + 16 + 8 * lh);
    }
  }

  // ---- w1: q prefetch + G fragments ----
  float4 pq4[16]; float pniq = 0.f;
  s16x8 pGf[2];
  f32x16 Xprev;
  auto qprefetch = [&](int cc) {
    const float4* q4 = (const float4*)(qh + (size_t)(cc * C + lr) * K_);
    #pragma unroll
    for (int kb = 0; kb < 8; ++kb) {
      pq4[2 * kb]     = q4[4 * kb + 2 * lh];
      pq4[2 * kb + 1] = q4[4 * kb + 2 * lh + 1];
    }
    pniq = ((const float*)(wsh + (size_t)cc * WSCH + 4096))[96 + lr];
  };

  // ---- stagers (w2/w3): k-hat + scalars only ----
  float4 pk[8]; float psc = 0.f;
  auto prefetch = [&](int cc) {
    const float4* k4 = (const float4*)(kh + (size_t)(cc * C + r4) * K_);
    #pragma unroll
    for (int j = 0; j < 8; ++j) pk[j] = k4[c4 + 4 * j];
    psc = (ts < 96) ? ((const float*)(wsh + (size_t)cc * WSCH + 4096))[ts] : 0.f;
  };
  auto stage = [&](int b, int b3) {
    float sk = 0.f;
    #pragma unroll
    for (int j = 0; j < 8; ++j)
      sk += pk[j].x*pk[j].x + pk[j].y*pk[j].y + pk[j].z*pk[j].z + pk[j].w*pk[j].w;
    sk += __shfl_xor(sk, 1); sk += __shfl_xor(sk, 2);
    const float nik = 1.0f / fmaxf(sqrtf(sk), 1e-12f);
    #pragma unroll
    for (int j = 0; j < 8; ++j) {
      const int f4 = c4 + 4 * j;
      uint2 upk;
      upk.x = cvtpk(pk[j].x * nik, pk[j].y * nik);
      upk.y = cvtpk(pk[j].z * nik, pk[j].w * nik);
      *(uint2*)(&Kh[b][0] + r4 * SK + 4 * f4) = upk;
      ushort* kt = &KhT[b][0] + (4 * f4) * SRT + r4;
      kt[0]       = (ushort)upk.x;
      kt[SRT]     = (ushort)(upk.x >> 16);
      kt[2 * SRT] = (ushort)upk.y;
      kt[3 * SRT] = (ushort)(upk.y >> 16);
    }
    if (ts < 32)      ls_eb[b3][ts]      = psc;
    else if (ts < 96) ls_bbf[b][ts - 32] = psc;
  };

  if (w >= 2)      { prefetch(0); stage(0, 0); prefetch(1); }
  else if (w == 1) { qprefetch(0); }
  bar_lds();

  #define MFMA __builtin_amdgcn_mfma_f32_32x32x16_bf16
  auto iter = [&](int ch, int cur, float* pvvC, float* pvvN, s16x8* pTfC, s16x8* pTfN) {
    const int nxt = cur ^ 1, c3 = ch % 3;
    if (w == 0) {
      // ---- prefetch next chunk's v and T into the alternate register buffers ----
      if (ch + 1 < NCH) {
        const float* vb = vh + (size_t)((ch + 1) * C) * V_ + v0 + lr;
        #pragma unroll
        for (int i = 0; i < 16; ++i) pvvN[i] = vb[(size_t)rowmap(i, lh) * V_];
        const ushort* Tg = (const ushort*)(wsh + (size_t)(ch + 1) * WSCH);
        pTfN[0] = *(const s16x8*)(Tg + lr * 32 + 8 * lh);
        pTfN[1] = *(const s16x8*)(Tg + lr * 32 + 16 + 8 * lh);
      }
      // ---- hoisted LDS operand reads (latency hides under W chain) ----
      s16x8 kt2[8];
      #pragma unroll
      for (int q = 0; q < 4; ++q) {
        kt2[2*q]   = ld8u(&KhT[cur][0] + (32 * q + lr) * SRT + 8 * lh);
        kt2[2*q+1] = ld8u(&KhT[cur][0] + (32 * q + lr) * SRT + 16 + 8 * lh);
      }
      float2 bbp[16];
      #pragma unroll
      for (int p = 0; p < 8; ++p) {
        int row = rowmap(2 * p, lh);
        bbp[2*p]   = ((const float2*)ls_bbf[cur])[row];
        bbp[2*p+1] = ((const float2*)ls_bbf[cur])[row + 1];
      }
      float tv[16];
      #pragma unroll
      for (int i = 0; i < 16; ++i) tv[i] = bbp[i].x * pvvC[i];
      // ---- W = Khat.S : 4 independent chains of 2 ----
      f32x16 wa0, wa1, wa2, wa3;
      #pragma unroll
      for (int i = 0; i < 16; ++i) { wa0[i]=0.f; wa1[i]=0.f; wa2[i]=0.f; wa3[i]=0.f; }
      const ushort* khc = &Kh[cur][0] + lr * SK + 8 * lh;
      wa0 = MFMA(*(const s16x8*)(khc +   0), Sfrag[0], wa0, 0, 0, 0);
      wa1 = MFMA(*(const s16x8*)(khc +  16), Sfrag[1], wa1, 0, 0, 0);
      wa2 = MFMA(*(const s16x8*)(khc +  32), Sfrag[2], wa2, 0, 0, 0);
      wa3 = MFMA(*(const s16x8*)(khc +  48), Sfrag[3], wa3, 0, 0, 0);
      wa0 = MFMA(*(const s16x8*)(khc +  64), Sfrag[4], wa0, 0, 0, 0);
      wa1 = MFMA(*(const s16x8*)(khc +  80), Sfrag[5], wa1, 0, 0, 0);
      wa2 = MFMA(*(const s16x8*)(khc +  96), Sfrag[6], wa2, 0, 0, 0);
      wa3 = MFMA(*(const s16x8*)(khc + 112), Sfrag[7], wa3, 0, 0, 0);
      f32x16 Wacc = (wa0 + wa1) + (wa2 + wa3);
      // ---- B = bev*v - bet*W ----
      f32x16 Bv;
      #pragma unroll
      for (int i = 0; i < 16; ++i) Bv[i] = tv[i] - bbp[i].y * Wacc[i];
      u32 ub[8]; packq(Bv, ub);
      s16x8 bf0, bf1; swapfr(ub, bf0, bf1);
      // ---- U = T.B (T fragments from registers) ----
      f32x16 Uacc;
      #pragma unroll
      for (int i = 0; i < 16; ++i) Uacc[i] = 0.f;
      Uacc = MFMA(pTfC[0], bf0, Uacc, 0, 0, 0);
      Uacc = MFMA(pTfC[1], bf1, Uacc, 0, 0, 0);
      u32 uu[8]; packq(Uacc, uu);
      #pragma unroll
      for (int p = 0; p < 8; ++p)
        *(u32*)(&UT[cur][0] + lr * SRU + rowmap(2 * p, lh)) = uu[p];
      s16x8 uf0, uf1; swapfr(uu, uf0, uf1);
      // ---- state update (4 independent quadrants) ----
      const float ebL = ls_eb[c3][31];
      #pragma unroll
      for (int q = 0; q < 4; ++q) {
        f32x16 acc = Sst[q];
        acc = MFMA(kt2[2*q],   uf0, acc, 0, 0, 0);
        acc = MFMA(kt2[2*q+1], uf1, acc, 0, 0, 0);
        #pragma unroll
        for (int i = 0; i < 16; ++i) Sst[q][i] = ebL * acc[i];
        u32 us[8]; packq(Sst[q], us);
        #pragma unroll
        for (int p = 0; p < 8; ++p)
          *(u32*)(&SbT[nxt][0] + lr * SK + 32 * q + rowmap(2 * p, lh)) = us[p];
        swapfr(us, Sfrag[2 * q], Sfrag[2 * q + 1]);
      }
    } else if (w == 1) {
      // ---- X = Qhat.S from global-q fragments: 4 chains of 2 ----
      f32x16 x0, x1, x2, x3;
      #pragma unroll
      for (int i = 0; i < 16; ++i) { x0[i]=0.f; x1[i]=0.f; x2[i]=0.f; x3[i]=0.f; }
      #pragma unroll
      for (int kb = 0; kb < 8; ++kb) {
        u32 ca = cvtpk(pq4[2*kb].x * pniq,   pq4[2*kb].y * pniq);
        u32 cb = cvtpk(pq4[2*kb].z * pniq,   pq4[2*kb].w * pniq);
        u32 cc2 = cvtpk(pq4[2*kb+1].x * pniq, pq4[2*kb+1].y * pniq);
        u32 cd = cvtpk(pq4[2*kb+1].z * pniq, pq4[2*kb+1].w * pniq);
        s16x8 qa = __builtin_bit_cast(s16x8, make_int4((int)ca,(int)cb,(int)cc2,(int)cd));
        s16x8 sb = *(const s16x8*)(&SbT[cur][0] + lr * SK + 16 * kb + 8 * lh);
        switch (kb & 3) {
          case 0: x0 = MFMA(qa, sb, x0, 0, 0, 0); break;
          case 1: x1 = MFMA(qa, sb, x1, 0, 0, 0); break;
          case 2: x2 = MFMA(qa, sb, x2, 0, 0, 0); break;
          default: x3 = MFMA(qa, sb, x3, 0, 0, 0); break;
        }
      }
      f32x16 Xn = (x0 + x1) + (x2 + x3);
      if (ch > 0) {   // lagged O for chunk ch-1 (G fragments prefetched last iter)
        const int pc = nxt, p3 = (ch - 1) % 3, tp = (ch - 1) * C;
        f32x16 Oacc = Xprev;
        Oacc = MFMA(pGf[0], ld8u(&UT[pc][0] + lr * SRU + 8 * lh),      Oacc, 0, 0, 0);
        Oacc = MFMA(pGf[1], ld8u(&UT[pc][0] + lr * SRU + 16 + 8 * lh), Oacc, 0, 0, 0);
        #pragma unroll
        for (int i = 0; i < 16; ++i) {
          const int row = rowmap(i, lh);
          oh[(size_t)(tp + row) * V_ + v0 + lr] = ls_eb[p3][row] * Oacc[i];
        }
      }
      Xprev = Xn;
      { // load G(ch) fragments for next iteration's O
        const ushort* Gg = (const ushort*)(wsh + (size_t)ch * WSCH + 2048);
        pGf[0] = *(const s16x8*)(Gg + lr * 32 + 8 * lh);
        pGf[1] = *(const s16x8*)(Gg + lr * 32 + 16 + 8 * lh);
      }
      if (ch + 1 < NCH) qprefetch(ch + 1);
    } else {
      if (ch + 1 < NCH) stage(nxt, (ch + 1) % 3);
      if (ch + 2 < NCH) prefetch(ch + 2);
    }
    bar_lds();
  };

  for (int ch = 0; ch < NCH; ch += 2) {
    iter(ch,     0, pvvA, pvvB, pTfA, pTfB);
    iter(ch + 1, 1, pvvB, pvvA, pTfB, pTfA);
  }
  #undef MFMA

  // epilogue: O for the last chunk
  if (w == 1) {
    const int pc = (NCH - 1) & 1, p3 = (NCH - 1) % 3, tp = (NCH - 1) * C;
    f32x16 Oacc = Xprev;
    Oacc = __builtin_amdgcn_mfma_f32_32x32x16_bf16(
        pGf[0], ld8u(&UT[pc][0] + lr * SRU + 8 * lh), Oacc, 0, 0, 0);
    Oacc = __builtin_amdgcn_mfma_f32_32x32x16_bf16(
        pGf[1], ld8u(&UT[pc][0] + lr * SRU + 16 + 8 * lh), Oacc, 0, 0, 0);
    #pragma unroll
    for (int i = 0; i < 16; ++i) {
      const int row = rowmap(i, lh);
      oh[(size_t)(tp + row) * V_ + v0 + lr] = ls_eb[p3][row] * Oacc[i];
    }
  }
  // final state from w0 registers
  if (w == 0) {
    #pragma unroll
    for (int q = 0; q < 4; ++q) {
      float* sp = out + (size_t)BHn * T_ * V_
                      + ((size_t)bh * K_ + 32 * q) * V_ + v0 + lr;
      #pragma unroll
      for (int i = 0; i < 16; ++i)
        sp[(size_t)rowmap(i, lh) * V_] = Sst[q][i];
    }
  }
}

extern "C" void kernel_launch(void* const* d_in, const int* in_sizes, int n_in,
                              void* d_out, int out_size, void* d_ws, size_t ws_size,
                              hipStream_t stream) {
  const float* q    = (const float*)d_in[0];
  const float* k    = (const float*)d_in[1];
  const float* v    = (const float*)d_in[2];
  const float* g    = (const float*)d_in[3];
  const float* beta = (const float*)d_in[4];
  const float* s0   = (const float*)d_in[5];
  float* out = (float*)d_out;
  char* ws = (char*)d_ws;   // 64*64*4608 = 18.9 MB
  hipLaunchKernelGGL(gdn_pre_kernel, dim3(BHn * NCH), dim3(256), 0, stream,
                     q, k, g, beta, ws);
  hipLaunchKernelGGL(gdn_seq_kernel, dim3(BHn * NS), dim3(256), 0, stream,
                     q, k, v, s0, ws, out);
}